// Round 6
// baseline (1727.397 us; speedup 1.0000x reference)
//
#include <hip/hip_runtime.h>
#include <math.h>

// ============================================================================
// RetrievalAugmentedProcessor — MI355X (gfx950)
// B=4 S=2048 D=1024 R=3 K=256 MAXR=256 H=8 HD=128
// R15: R14 post-mortem — 256x128 tile @1 block/CU regressed (111us vs 79):
//     with one block, the per-step vmcnt(0) drain is fully exposed (R11's
//     speed came from 2 blocks/CU covering each other's drain). Fix: T4
//     counted-vmcnt 3-buffer pipeline. Per K-step:
//       wait vmcnt(NLD) [buf k done, buf k+1's NLD loads stay in flight
//       ACROSS the barrier] ; barrier ; STAGE(buf k+2) ; ds_read k ; MFMA.
//     Each tile's loads get 2 compute phases to land. WAR on buf[k-1] is
//     fenced by the barrier (reads consumed before each wave reached it).
//     Final iters wait vmcnt(0). LDS: split 3x48KB=144KB (1 blk/CU),
//     plain BM=256 72KB, BM=128 48KB (2 blk/CU for z-batched attn GEMMs).
//     MFMA order per output unchanged -> bit-identical numerics.
// Layout (MB):  0..24 qgT[A] | 24..40 xh[A,F] | 40..56 xl[A] | 56..72 qfh(r)
//   | 72..88 qfl(r) | 88..120 t1[A scratch, 32MB] / scoresA[B]@88 +
//   scoresB[B]@104 / hbuf[D]@88 / Sattn[F]@88 | 120.. smalls
// Overlays: rh@0 rl@6 relT@12 seltok@14 kbuf@16 VT@18 [D/E] (over dead qgT);
//   inT@40 outT@46 qbuf@56 fused@72 attnout@0 [F]. Peak 120MB <= 131.
// ============================================================================

typedef unsigned short u16;
typedef unsigned int   u32;
typedef __attribute__((ext_vector_type(8))) short short8;   // 8 bf16
typedef __attribute__((ext_vector_type(4))) float f32x4;    // MFMA acc
typedef __attribute__((ext_vector_type(4))) u16  u16x4;

__device__ __forceinline__ float b2f(u16 u){ union{float f;u32 i;} x; x.i=((u32)u)<<16; return x.f; }
__device__ __forceinline__ u16 f2b(float f){ union{float f;u32 i;} x; x.f=f; u32 r=x.i+0x7fffu+((x.i>>16)&1u); return (u16)(r>>16); }
__device__ __forceinline__ float gelu_f(float v){ return 0.5f*v*(1.f+erff(v*0.70710678118654752f)); }

__device__ __forceinline__ void load_lds16(const u16* g, u16* l){
  __builtin_amdgcn_global_load_lds((const __attribute__((address_space(1))) u32*)g,
                                   (__attribute__((address_space(3))) u32*)l, 16, 0, 0);
}

// counted waitcnt with compile-time immediate
template<int N>
__device__ __forceinline__ void wait_vm(){
  if constexpr (N>=12)     asm volatile("s_waitcnt vmcnt(12)" ::: "memory");
  else if constexpr (N==8) asm volatile("s_waitcnt vmcnt(8)"  ::: "memory");
  else if constexpr (N==6) asm volatile("s_waitcnt vmcnt(6)"  ::: "memory");
  else if constexpr (N==4) asm volatile("s_waitcnt vmcnt(4)"  ::: "memory");
  else                     asm volatile("s_waitcnt vmcnt(0)"  ::: "memory");
}

// ---------------- reductions ----------------
__device__ __forceinline__ float waveRedSum(float v){
  #pragma unroll
  for (int o=32;o>0;o>>=1) v += __shfl_xor(v,o);
  return v;
}
__device__ __forceinline__ float waveRedMax(float v){
  #pragma unroll
  for (int o=32;o>0;o>>=1) v = fmaxf(v, __shfl_xor(v,o));
  return v;
}
__device__ float blockRedSum(float v){
  __shared__ float tmp[17];
  const int lane = threadIdx.x&63, wv = threadIdx.x>>6, nw = blockDim.x>>6;
  v = waveRedSum(v);
  __syncthreads();
  if (lane==0) tmp[wv]=v;
  __syncthreads();
  if (threadIdx.x==0){ float s=tmp[0]; for(int i=1;i<nw;i++) s+=tmp[i]; tmp[16]=s; }
  __syncthreads();
  return tmp[16];
}
__device__ float blockRedMax(float v){
  __shared__ float tmp[17];
  const int lane = threadIdx.x&63, wv = threadIdx.x>>6, nw = blockDim.x>>6;
  v = waveRedMax(v);
  __syncthreads();
  if (lane==0) tmp[wv]=v;
  __syncthreads();
  if (threadIdx.x==0){ float s=tmp[0]; for(int i=1;i<nw;i++) s=fmaxf(s,tmp[i]); tmp[16]=s; }
  __syncthreads();
  return tmp[16];
}

// ============================================================================
// Plain bf16 NT GEMM, global_load_lds staging, 3-buffer counted-vmcnt pipeline.
enum { EPI_NONE=0, EPI_BIAS=1, EPI_SCALE=3, EPI_VT=5 };

template<int EPI, int BM>
__global__ __launch_bounds__(256,(BM==128)?2:1)
void gemm_nt(const u16* __restrict__ Ag, long long lda, long long sA1, long long sA2,
             const u16* __restrict__ Bg, long long ldb, long long sB1, long long sB2,
             u16* __restrict__ Cg, long long ldc, long long sC1, long long sC2,
             const float* __restrict__ bias, long long sBias,
             float scale, int K, int H)
{
  constexpr int NA   = BM/64;     // A stage chunks (64 rows) per buffer
  constexpr int MI   = BM/32;     // acc i-frags per wave
  constexpr int ABUF = BM*32;     // u16 per A buffer
  constexpr int NLD  = NA + 2;    // loads per stage per thread
  __shared__ u16 As[3*ABUF];
  __shared__ u16 Bs[3*4096];
  const int z  = blockIdx.z;
  const int zb = z / H, zh = z - zb*H;
  const u16* A = Ag + zb*sA1 + zh*sA2;
  const u16* B = Bg + zb*sB1 + zh*sB2;
  const int m0 = blockIdx.y*BM, n0 = blockIdx.x*128;
  const int t  = threadIdx.x;
  const int lane = t & 63, wv = t >> 6;
  const int wm = (wv>>1)*(BM/2), wn = (wv&1)*64;

  const long long arow = (long long)(m0 + (t>>2))*lda + (t&3)*8;
  const long long brow = (long long)(n0 + (t>>2))*ldb + (t&3)*8;
  const u16* ga[NA]; const u16* gb[2];
  #pragma unroll
  for (int q=0;q<NA;q++) ga[q] = A + arow + (long long)q*64*lda;
  #pragma unroll
  for (int q=0;q<2;q++)  gb[q] = B + brow + (long long)q*64*ldb;
  u16* lA_t = As + t*8;
  u16* lB_t = Bs + t*8;

  f32x4 acc[MI][4];
  #pragma unroll
  for (int i=0;i<MI;i++)
    #pragma unroll
    for (int j=0;j<4;j++) acc[i][j] = (f32x4){0.f,0.f,0.f,0.f};

  const int foff = (lane&15)*32 + ((lane>>4)*8);
  const short8* arp = (const short8*)(As + wm*32 + foff);
  const short8* brp = (const short8*)(Bs + wn*32 + foff);

  auto STAGE = [&](int bi){
    const int boA = bi*ABUF, boB = bi*4096;
    #pragma unroll
    for (int q=0;q<NA;q++){ load_lds16(ga[q], lA_t + boA + q*2048); ga[q] += 32; }
    #pragma unroll
    for (int q=0;q<2;q++) { load_lds16(gb[q], lB_t + boB + q*2048); gb[q] += 32; }
  };

  const int nk = K >> 5;
  STAGE(0); STAGE(1);
  int cur = 0;
  for (int kk = 0; kk < nk; ++kk) {
    if (kk + 1 < nk) wait_vm<NLD>(); else wait_vm<0>();
    __builtin_amdgcn_s_barrier();
    if (kk + 2 < nk) STAGE(cur==0 ? 2 : cur-1);   // (cur+2)%3
    const int boSA = cur*(ABUF/8);
    const int boSB = cur*512;
    short8 af[MI], bfr[4];
    #pragma unroll
    for (int i=0;i<MI;i++) af[i]  = arp[boSA + i*64];
    #pragma unroll
    for (int j=0;j<4;j++)  bfr[j] = brp[boSB + j*64];
    #pragma unroll
    for (int i=0;i<MI;i++)
      #pragma unroll
      for (int j=0;j<4;j++)
        acc[i][j] = __builtin_amdgcn_mfma_f32_16x16x32_bf16(af[i], bfr[j], acc[i][j], 0, 0, 0);
    cur = (cur==2) ? 0 : cur+1;
  }

  u16* C = Cg + zb*sC1 + zh*sC2;
  const float* bz = bias + zb*sBias;
  const int rb0 = m0 + wm + ((lane>>4)<<2);
  const int cb0 = n0 + wn + (lane&15);
  #pragma unroll
  for (int j=0;j<4;j++){
    const int cn = cb0 + j*16;
    float bv = 0.f;
    if constexpr (EPI==EPI_BIAS || EPI==EPI_VT) bv = bz[cn];
    #pragma unroll
    for (int i=0;i<MI;i++){
      #pragma unroll
      for (int p=0;p<4;p++){
        const int row = rb0 + i*16 + p;
        float v = acc[i][j][p];
        if constexpr (EPI==EPI_SCALE) v *= scale;
        if constexpr (EPI==EPI_BIAS)  v += bv;
        if constexpr (EPI==EPI_VT) {
          v += bv;
          const int bb = row>>8, tt = row&255, hh = cn>>7, dd = cn&127;
          C[((long long)((bb*8+hh)*128+dd)<<8) + tt] = f2b(v);
        } else {
          C[(long long)row*ldc + cn] = f2b(v);
        }
      }
    }
  }
}

// ============================================================================
// Split-bf16 NT GEMM: acc += Al*Bh + Ah*Bl + Ah*Bh. 3-buffer counted-vmcnt.
enum { SP_GELU_SPLIT=0, SP_BIAS_SPLIT=1, SP_SCALE_F32=2, SP_QBG_F32=3 };

template<int EPI, int BM>
__global__ __launch_bounds__(256,1)
void gemm_nt_split(const u16* __restrict__ Ah_, const u16* __restrict__ Al_, long long lda, long long sAz,
                   const u16* __restrict__ Bh_, const u16* __restrict__ Bl_, long long ldb, long long sBz,
                   void* __restrict__ C0, void* __restrict__ C1, long long ldc, long long sCz,
                   const float* __restrict__ bias, float scale, int K)
{
  constexpr int NA   = BM/64;
  constexpr int MI   = BM/32;
  constexpr int ABUF = BM*32;
  constexpr int NLD  = NA*2 + 4;   // loads per stage per thread
  __shared__ u16 AsH[3*ABUF];
  __shared__ u16 AsL[3*ABUF];
  __shared__ u16 BsH[3*4096];
  __shared__ u16 BsL[3*4096];
  const int z = blockIdx.z;
  const int m0 = blockIdx.y*BM, n0 = blockIdx.x*128;
  const int t  = threadIdx.x;
  const int lane = t & 63, wv = t >> 6;
  const int wm = (wv>>1)*(BM/2), wn = (wv&1)*64;

  const long long arow = (long long)z*sAz + (long long)(m0 + (t>>2))*lda + (t&3)*8;
  const long long brow = (long long)z*sBz + (long long)(n0 + (t>>2))*ldb + (t&3)*8;
  const u16* gah[NA]; const u16* gal[NA];
  const u16* gbh[2];  const u16* gbl[2];
  #pragma unroll
  for (int q=0;q<NA;q++){
    gah[q] = Ah_ + arow + (long long)q*64*lda;
    gal[q] = Al_ + arow + (long long)q*64*lda;
  }
  #pragma unroll
  for (int q=0;q<2;q++){
    gbh[q] = Bh_ + brow + (long long)q*64*ldb;
    gbl[q] = Bl_ + brow + (long long)q*64*ldb;
  }
  u16* lAh_t = AsH + t*8;  u16* lAl_t = AsL + t*8;
  u16* lBh_t = BsH + t*8;  u16* lBl_t = BsL + t*8;

  f32x4 acc[MI][4];
  #pragma unroll
  for (int i=0;i<MI;i++)
    #pragma unroll
    for (int j=0;j<4;j++) acc[i][j] = (f32x4){0.f,0.f,0.f,0.f};

  const int foff = (lane&15)*32 + ((lane>>4)*8);
  const short8* arh = (const short8*)(AsH + wm*32 + foff);
  const short8* arl = (const short8*)(AsL + wm*32 + foff);
  const short8* brh = (const short8*)(BsH + wn*32 + foff);
  const short8* brl = (const short8*)(BsL + wn*32 + foff);

  auto STAGE = [&](int bi){
    const int boA = bi*ABUF, boB = bi*4096;
    #pragma unroll
    for (int q=0;q<NA;q++){
      load_lds16(gah[q], lAh_t + boA + q*2048);
      load_lds16(gal[q], lAl_t + boA + q*2048);
      gah[q] += 32; gal[q] += 32;
    }
    #pragma unroll
    for (int q=0;q<2;q++){
      load_lds16(gbh[q], lBh_t + boB + q*2048);
      load_lds16(gbl[q], lBl_t + boB + q*2048);
      gbh[q] += 32; gbl[q] += 32;
    }
  };

  const int nk = K >> 5;
  STAGE(0); STAGE(1);
  int cur = 0;
  for (int kk = 0; kk < nk; ++kk) {
    if (kk + 1 < nk) wait_vm<NLD>(); else wait_vm<0>();
    __builtin_amdgcn_s_barrier();
    if (kk + 2 < nk) STAGE(cur==0 ? 2 : cur-1);   // (cur+2)%3
    const int boSA = cur*(ABUF/8);
    const int boSB = cur*512;
    short8 fah[MI], fal[MI], fbh[4], fbl[4];
    #pragma unroll
    for (int i=0;i<MI;i++){ fah[i]=arh[boSA+i*64]; fal[i]=arl[boSA+i*64]; }
    #pragma unroll
    for (int j=0;j<4;j++){ fbh[j]=brh[boSB+j*64]; fbl[j]=brl[boSB+j*64]; }
    #pragma unroll
    for (int i=0;i<MI;i++)
      #pragma unroll
      for (int j=0;j<4;j++){
        acc[i][j] = __builtin_amdgcn_mfma_f32_16x16x32_bf16(fal[i], fbh[j], acc[i][j], 0, 0, 0);
        acc[i][j] = __builtin_amdgcn_mfma_f32_16x16x32_bf16(fah[i], fbl[j], acc[i][j], 0, 0, 0);
        acc[i][j] = __builtin_amdgcn_mfma_f32_16x16x32_bf16(fah[i], fbh[j], acc[i][j], 0, 0, 0);
      }
    cur = (cur==2) ? 0 : cur+1;
  }

  const int rb0 = m0 + wm + ((lane>>4)<<2);
  const int cb0 = n0 + wn + (lane&15);
  #pragma unroll
  for (int j=0;j<4;j++){
    const int cn = cb0 + j*16;
    float bv = 0.f;
    if constexpr (EPI==SP_GELU_SPLIT || EPI==SP_BIAS_SPLIT) bv = bias[cn];
    #pragma unroll
    for (int i=0;i<MI;i++){
      #pragma unroll
      for (int p=0;p<4;p++){
        const int row = rb0 + i*16 + p;
        float v = acc[i][j][p];
        const long long o = (long long)z*sCz + (long long)row*ldc + cn;
        if constexpr (EPI==SP_GELU_SPLIT || EPI==SP_BIAS_SPLIT){
          v += bv;
          if constexpr (EPI==SP_GELU_SPLIT) v = gelu_f(v);
          const u16 h = f2b(v);
          ((u16*)C0)[o] = h;
          ((u16*)C1)[o] = f2b(v - b2f(h));
        }
        if constexpr (EPI==SP_SCALE_F32) ((float*)C0)[o] = v*scale;
        if constexpr (EPI==SP_QBG_F32)   ((float*)C0)[o] = gelu_f(v + bias[(row>>8)*512 + cn]);
      }
    }
  }
}

// ---------------- prep kernels ----------------
__global__ void transpose_w(const float* __restrict__ in, u16* __restrict__ out, int rows, int cols){
  __shared__ float tl[32][33];
  const long long zo = (long long)blockIdx.z*rows*cols;
  const int c0 = blockIdx.x*32, r0 = blockIdx.y*32;
  const int tx = threadIdx.x, ty = threadIdx.y;
  #pragma unroll
  for (int yy=ty; yy<32; yy+=8) tl[yy][tx] = in[zo + (long long)(r0+yy)*cols + (c0+tx)];
  __syncthreads();
  #pragma unroll
  for (int yy=ty; yy<32; yy+=8) out[zo + (long long)(c0+yy)*rows + (r0+tx)] = f2b(tl[tx][yy]);
}

__global__ void split_transpose_w(const float* __restrict__ in, u16* __restrict__ outH,
                                  u16* __restrict__ outL, int rows, int cols){
  __shared__ float tl[32][33];
  const long long zo = (long long)blockIdx.z*rows*cols;
  const int c0 = blockIdx.x*32, r0 = blockIdx.y*32;
  const int tx = threadIdx.x, ty = threadIdx.y;
  #pragma unroll
  for (int yy=ty; yy<32; yy+=8) tl[yy][tx] = in[zo + (long long)(r0+yy)*cols + (c0+tx)];
  __syncthreads();
  #pragma unroll
  for (int yy=ty; yy<32; yy+=8){
    const float v = tl[tx][yy];
    const u16 h = f2b(v);
    const long long o = zo + (long long)(c0+yy)*rows + (r0+tx);
    outH[o] = h;
    outL[o] = f2b(v - b2f(h));
  }
}

__global__ void split_f32_k(const float* __restrict__ in, u16* __restrict__ oh,
                            u16* __restrict__ ol, int n4){
  const int i = blockIdx.x*256 + threadIdx.x;
  if (i < n4){
    const float4 v = ((const float4*)in)[i];
    u16x4 hh, ll;
    hh.x=f2b(v.x); ll.x=f2b(v.x-b2f(hh.x));
    hh.y=f2b(v.y); ll.y=f2b(v.y-b2f(hh.y));
    hh.z=f2b(v.z); ll.z=f2b(v.z-b2f(hh.z));
    hh.w=f2b(v.w); ll.w=f2b(v.w-b2f(hh.w));
    ((u16x4*)oh)[i] = hh;
    ((u16x4*)ol)[i] = ll;
  }
}

__global__ void zero_f32(float* __restrict__ p, int n){
  const int i = blockIdx.x*256 + threadIdx.x;
  if (i < n) p[i] = 0.f;
}

__global__ void init_queries(const float* __restrict__ pb, float* __restrict__ q){
  const int i = blockIdx.x*256 + threadIdx.x;
  if (i < 12288) q[i] = pb[(i>>12)*1024 + (i&1023)];
}
__global__ void init_qpart(const float* __restrict__ rb1, float* __restrict__ qp){
  const int i = blockIdx.x*256 + threadIdx.x;
  if (i < 6144) qp[i] = rb1[i&511];
}

__global__ void ws_report(float* __restrict__ out, int n4, float val){
  const int i = blockIdx.x*256 + threadIdx.x;
  if (i < n4){
    float4 z; z.x = (i==0)? val : 0.f; z.y=0.f; z.z=0.f; z.w=0.f;
    ((float4*)out)[i] = z;
  }
}

// ---------------- pooling (fp32 scores) ----------------
__global__ void row_stats_f32(const float* __restrict__ S, float* __restrict__ mOut,
                              float* __restrict__ dOut){
  const int row = blockIdx.x;
  const float4* p = (const float4*)(S + (long long)row*2048);
  const int tid = threadIdx.x;
  const float4 a = p[2*tid], b = p[2*tid+1];
  float v[8] = {a.x,a.y,a.z,a.w,b.x,b.y,b.z,b.w};
  float mx = v[0];
  #pragma unroll
  for (int k=1;k<8;k++) mx = fmaxf(mx, v[k]);
  mx = blockRedMax(mx);
  float s = 0.f;
  #pragma unroll
  for (int k=0;k<8;k++) s += expf(v[k]-mx);
  s = blockRedSum(s);
  if (tid==0){ mOut[row]=mx; dOut[row]=s; }
}

__global__ void col_mean_f32(const float* __restrict__ S, const float* __restrict__ m,
                             const float* __restrict__ den, float* __restrict__ w){
  const int tc = blockIdx.x*256 + threadIdx.x;
  const int s0 = blockIdx.y*64;
  const float* p = S + (long long)s0*2048 + tc;
  float acc = 0.f;
  for (int s=0;s<64;s++)
    acc += expf(p[(long long)s<<11] - m[s0+s]) * (1.0f/den[s0+s]);
  atomicAdd(&w[tc], acc * (1.f/2048.f));
}

// pooled[b][d] += tile sums; grid (4,16) per retriever (R6-proven)
__global__ __launch_bounds__(256)
void pooled_par(const u16* __restrict__ qfh, const u16* __restrict__ qfl,
                const float* __restrict__ w, float* __restrict__ pooled){
  const int b = blockIdx.x, tt0 = blockIdx.y*128;
  const int t = threadIdx.x;
  __shared__ float wsh[128];
  if (t < 128) wsh[t] = w[b*2048 + tt0 + t];
  __syncthreads();
  const long long base = (long long)b*2097152 + (long long)tt0*1024;
  const u16* ph = qfh + base;
  const u16* pl = qfl + base;
  float acc[4] = {0.f,0.f,0.f,0.f};
  for (int s=0; s<128; s++){
    const float wt = wsh[s];
    const long long o = (long long)s*1024;
    #pragma unroll
    for (int k=0;k<4;k++){
      const int dd = t + k*256;
      acc[k] += wt*(b2f(ph[o+dd]) + b2f(pl[o+dd]));
    }
  }
  #pragma unroll
  for (int k=0;k<4;k++) atomicAdd(&pooled[b*1024 + t + k*256], acc[k]);
}

__global__ __launch_bounds__(1024)
void pool_ln(const float* __restrict__ pooled, const float* __restrict__ pg,
             const float* __restrict__ pb, float* __restrict__ plbuf){
  const int z = blockIdx.x, r = z>>2, d = threadIdx.x;
  const float v = pooled[z*1024+d];
  const float mean = blockRedSum(v) * (1.f/1024.f);
  const float df = v - mean;
  const float var = blockRedSum(df*df) * (1.f/1024.f);
  plbuf[z*1024+d] = df*rsqrtf(var+1e-5f)*pg[r*1024+d] + pb[r*1024+d];
}

__global__ __launch_bounds__(256)
void query_accum(const float* __restrict__ plbuf, const float* __restrict__ pw,
                 float* __restrict__ queries){
  const int z = blockIdx.x, r = z>>2, k0 = blockIdx.y*32;
  const int t = threadIdx.x;
  __shared__ float pls[32];
  if (t < 32) pls[t] = plbuf[z*1024 + k0 + t];
  __syncthreads();
  const float* wp = pw + (long long)r*1048576 + (long long)k0*1024;
  float acc[4] = {0.f,0.f,0.f,0.f};
  for (int s=0;s<32;s++){
    const float wv = pls[s];
    #pragma unroll
    for (int c=0;c<4;c++) acc[c] += wv*wp[s*1024 + t + c*256];
  }
  #pragma unroll
  for (int c=0;c<4;c++) atomicAdd(&queries[z*1024 + t + c*256], acc[c]);
}

__global__ __launch_bounds__(256)
void qpart_accum(const float* __restrict__ queries, const float* __restrict__ rw1,
                 float* __restrict__ qpart){
  const int z = blockIdx.x, k0 = blockIdx.y*64;
  const int t = threadIdx.x;
  __shared__ float qs[64];
  if (t < 64) qs[t] = queries[z*1024 + k0 + t];
  __syncthreads();
  const float* wp = rw1 + 1024*512 + (long long)k0*512;
  float acc[2] = {0.f,0.f};
  for (int s=0;s<64;s++){
    const float wv = qs[s];
    #pragma unroll
    for (int c=0;c<2;c++) acc[c] += wv*wp[s*512 + t + c*256];
  }
  #pragma unroll
  for (int c=0;c<2;c++) atomicAdd(&qpart[z*512 + t + c*256], acc[c]);
}

__global__ void rel_score_f32(const float* __restrict__ h, const float* __restrict__ w2,
                              const float* __restrict__ b2p, float* __restrict__ relv){
  const int row = blockIdx.x*4 + (threadIdx.x>>6);
  const int lane = threadIdx.x & 63;
  const float* p = h + (long long)row*512;
  float a = 0.f;
  #pragma unroll
  for (int k=0;k<8;k++){ const int idx = lane + k*64; a += p[idx]*w2[idx]; }
  a = waveRedSum(a);
  if (lane==0){
    const float lg = a + b2p[0];
    relv[row] = 1.f/(1.f+expf(-lg));
  }
}

// ---------------- selection ----------------
__global__ __launch_bounds__(768)
void select_topk(const float* __restrict__ relv, int* __restrict__ selidx,
                 int* __restrict__ neff, int* __restrict__ anyv){
  const int b = blockIdx.x, c = threadIdx.x;
  __shared__ float rv[768];
  __shared__ int cnt;
  rv[c] = relv[(((c>>8)*4)+b)*256 + (c&255)];
  if (c==0) cnt = 0;
  __syncthreads();
  const float mine = rv[c];
  const bool valid = (mine >= 0.5f);
  int rank = 0;
  for (int j=0;j<768;j++){
    const float vj = rv[j];
    if (vj >= 0.5f && (vj > mine || (vj == mine && j < c))) rank++;
  }
  if (valid && rank < 256){
    const int s = atomicAdd(&cnt, 1);
    selidx[b*256 + s] = c;
  }
  __syncthreads();
  if (c==0){ neff[b] = cnt; anyv[b] = (cnt>0) ? 1 : 0; }
}

__global__ void gather_sel(const u16* __restrict__ rb16, const int* __restrict__ selidx,
                           const int* __restrict__ neff, u16* __restrict__ seltok){
  const int slot = blockIdx.x, b = blockIdx.y, tid = threadIdx.x;
  uint2 val; val.x=0u; val.y=0u;
  if (slot < neff[b]){
    const int c = selidx[b*256+slot];
    const uint2* src = (const uint2*)(rb16 + (long long)(((c>>8)*4+b)*256 + (c&255))*1024);
    val = src[tid];
  }
  ((uint2*)(seltok + (long long)(b*256+slot)*1024))[tid] = val;
}

__global__ void attn_softmax(u16* __restrict__ S, const int* __restrict__ neff){
  const int ri = blockIdx.x*4 + (threadIdx.x>>6);
  const int lane = threadIdx.x & 63;
  const int b = ri >> 14;
  const int ne = neff[b];
  u16* p = S + (long long)ri*256 + lane*4;
  if (ne == 0){ uint2 zz; zz.x=0u; zz.y=0u; *(uint2*)p = zz; return; }
  uint2 raw = *(const uint2*)p;
  u16 uu[4] = {(u16)(raw.x&0xffffu),(u16)(raw.x>>16),(u16)(raw.y&0xffffu),(u16)(raw.y>>16)};
  float xs[4];
  #pragma unroll
  for (int q2=0;q2<4;q2++){ const int tt = lane*4+q2; xs[q2] = (tt<ne)? b2f(uu[q2]) : -1e30f; }
  float mx = fmaxf(fmaxf(xs[0],xs[1]),fmaxf(xs[2],xs[3]));
  mx = waveRedMax(mx);
  float e[4]; float sm=0.f;
  #pragma unroll
  for (int q2=0;q2<4;q2++){ e[q2] = (lane*4+q2<ne)? expf(xs[q2]-mx) : 0.f; sm += e[q2]; }
  sm = waveRedSum(sm);
  const float inv = 1.f/sm;
  #pragma unroll
  for (int q2=0;q2<4;q2++) uu[q2] = f2b(e[q2]*inv);
  raw.x = (u32)uu[0] | ((u32)uu[1]<<16);
  raw.y = (u32)uu[2] | ((u32)uu[3]<<16);
  *(uint2*)p = raw;
}

__global__ void final_ln(const float* __restrict__ x, const u16* __restrict__ fused,
                         const float* __restrict__ g, const float* __restrict__ bb,
                         const int* __restrict__ anyv, float* __restrict__ out){
  const int row = blockIdx.x; const int b = row>>11; const int tid = threadIdx.x;
  const float4 xv = ((const float4*)(x + (long long)row*1024))[tid];
  const uint2 fv = ((const uint2*)(fused + (long long)row*1024))[tid];
  const float e0 = xv.x + b2f((u16)(fv.x&0xffffu));
  const float e1 = xv.y + b2f((u16)(fv.x>>16));
  const float e2 = xv.z + b2f((u16)(fv.y&0xffffu));
  const float e3 = xv.w + b2f((u16)(fv.y>>16));
  const float mean = blockRedSum(e0+e1+e2+e3) * (1.f/1024.f);
  const float d0=e0-mean, d1=e1-mean, d2=e2-mean, d3=e3-mean;
  const float var = blockRedSum(d0*d0+d1*d1+d2*d2+d3*d3) * (1.f/1024.f);
  const float inv = rsqrtf(var + 1e-5f);
  const float4 gv = ((const float4*)g)[tid];
  const float4 bv = ((const float4*)bb)[tid];
  float4 o;
  if (anyv[b]){
    o.x = d0*inv*gv.x + bv.x; o.y = d1*inv*gv.y + bv.y;
    o.z = d2*inv*gv.z + bv.z; o.w = d3*inv*gv.w + bv.w;
  } else o = xv;
  ((float4*)(out + (long long)row*1024))[tid] = o;
}

// ============================================================================
extern "C" void kernel_launch(void* const* d_in, const int* in_sizes, int n_in,
                              void* d_out, int out_size, void* d_ws, size_t ws_size,
                              hipStream_t stream) {
  (void)in_sizes; (void)n_in;
  const float* x      = (const float*)d_in[0];
  const float* retr   = (const float*)d_in[1];
  const float* qg_w1  = (const float*)d_in[2];
  const float* qg_b1  = (const float*)d_in[3];
  const float* qg_w2  = (const float*)d_in[4];
  const float* qg_b2  = (const float*)d_in[5];
  const float* pln_g  = (const float*)d_in[6];
  const float* pln_b  = (const float*)d_in[7];
  const float* pool_w = (const float*)d_in[8];
  const float* pool_b = (const float*)d_in[9];
  const float* rel_w1 = (const float*)d_in[10];
  const float* rel_b1 = (const float*)d_in[11];
  const float* rel_w2 = (const float*)d_in[12];
  const float* rel_b2 = (const float*)d_in[13];
  const float* in_w   = (const float*)d_in[14];
  const float* in_b   = (const float*)d_in[15];
  const float* out_w  = (const float*)d_in[16];
  const float* out_b  = (const float*)d_in[17];
  const float* fln_g  = (const float*)d_in[18];
  const float* fln_b  = (const float*)d_in[19];
  float* out = (float*)d_out;
  char* ws = (char*)d_ws;

  const size_t MB = 1u<<20;
  const size_t REQUIRED = 131*MB;
  if (ws_size < REQUIRED){
    ws_report<<<(out_size/4 + 255)/256, 256, 0, stream>>>(out, out_size/4, (float)(ws_size>>20));
    return;
  }

  // ---- layout per header comment ----
  u16* qg1Th = (u16*)(ws + 0*MB);        // [P->A]
  u16* qg1Tl = (u16*)(ws + 6*MB);
  u16* qg2Th = (u16*)(ws + 12*MB);
  u16* qg2Tl = (u16*)(ws + 18*MB);
  u16* xh    = (u16*)(ws + 24*MB);       // [P->A,F]
  u16* xl    = (u16*)(ws + 40*MB);       // [P->A]
  u16* qfh   = (u16*)(ws + 56*MB);       // per-retriever [A->B]
  u16* qfl   = (u16*)(ws + 72*MB);
  u16* t1h   = (u16*)(ws + 88*MB);       // [A scratch, 16 MB = 8192x1024 bf16]
  u16* t1l   = (u16*)(ws + 104*MB);      // [A scratch, 16 MB]
  float* scoresA = (float*)(ws + 88*MB); // [B] over dead t1h
  float* scoresB = (float*)(ws + 104*MB);// [B] over dead t1l
  // stage D/E overlays (qg weights dead after stage A):
  u16* rh    = (u16*)(ws + 0*MB);        // 6  [D,E]
  u16* rl    = (u16*)(ws + 6*MB);        // 6  [D]
  u16* relTh = (u16*)(ws + 12*MB);       // 1  [D]
  u16* relTl = (u16*)(ws + 13*MB);       // 1  [D]
  u16* seltok= (u16*)(ws + 14*MB);       // 2  [E->F vproj]
  u16* kbuf  = (u16*)(ws + 16*MB);       // 2  [F, dead after QK^T]
  u16* VT    = (u16*)(ws + 18*MB);       // 2  [F, dead after AV]
  float* hbuf= (float*)(ws + 88*MB);     // 6  [D] over dead scoresA
  // stage F overlays:
  u16* inT   = (u16*)(ws + 40*MB);       // 6  over dead xl
  u16* outT  = (u16*)(ws + 46*MB);       // 2
  u16* qbuf  = (u16*)(ws + 56*MB);       // 16 over dead qfh
  u16* fused = (u16*)(ws + 72*MB);       // 16 over dead qfl
  u16* Sattn = (u16*)(ws + 88*MB);       // 32 over dead scores
  u16* attnout=(u16*)(ws + 0*MB);        // 16 over dead rh/rl/relT/seltok
  char* SM = ws + 120*MB;
  float* wbuf    = (float*)(SM);            // 96 KB [12][2048]
  float* pooledB = (float*)(SM + 98304);    // 48 KB
  float* plbuf   = (float*)(SM + 147456);   // 48 KB
  float* queries = (float*)(SM + 196608);   // 48 KB
  float* qpart   = (float*)(SM + 245760);   // 24 KB
  float* relv    = (float*)(SM + 270336);   // 12 KB
  int*   selidx  = (int*)(SM + 282624);
  int*   neff    = (int*)(SM + 286720);
  int*   anyv    = (int*)(SM + 286784);
  float* mrow0   = (float*)(SM + 286848);
  float* drow0   = (float*)(SM + 295040);
  float* mrow1   = (float*)(SM + 303232);
  float* drow1   = (float*)(SM + 311424);

  dim3 b256(256);
  dim3 tb(32,8);
  const long long SCZ = (long long)(16*MB)/4;   // scoresA -> scoresB (4,194,304 floats)

  // --- prep ---
  split_transpose_w<<<dim3(32,32,3), tb, 0, stream>>>(qg_w1, qg1Th, qg1Tl, 1024, 1024);
  split_transpose_w<<<dim3(32,32,3), tb, 0, stream>>>(qg_w2, qg2Th, qg2Tl, 1024, 1024);
  split_f32_k<<<8192, b256, 0, stream>>>(x, xh, xl, 2097152);
  zero_f32<<<144, b256, 0, stream>>>(wbuf, 36864);   // wbuf + pooledB

  // --- stages A+B interleaved per retriever (256x128 tiles, 3-buf pipeline) ---
  for (int r = 0; r < 3; r++){
    const long long wo = (long long)r*1048576;
    gemm_nt_split<SP_GELU_SPLIT,256><<<dim3(8,32,1), b256, 0, stream>>>(
        xh, xl, 1024, 0,  qg1Th+wo, qg1Tl+wo, 1024, 0,
        t1h, t1l, 1024, 0,  qg_b1+r*1024, 1.f, 1024);
    gemm_nt_split<SP_BIAS_SPLIT,256><<<dim3(8,32,1), b256, 0, stream>>>(
        t1h, t1l, 1024, 0,  qg2Th+wo, qg2Tl+wo, 1024, 0,
        qfh, qfl, 1024, 0,  qg_b2+r*1024, 1.f, 1024);
    for (int p2 = 0; p2 < 2; p2++){
      const long long qo = (long long)(p2*2)*2097152;
      gemm_nt_split<SP_SCALE_F32,256><<<dim3(16,8,2), b256, 0, stream>>>(
          qfh+qo, qfl+qo, 1024, 2097152,  qfh+qo, qfl+qo, 1024, 2097152,
          scoresA, nullptr, 2048, SCZ,  nullptr, 0.03125f, 1024);
      row_stats_f32<<<2048, b256, 0, stream>>>(scoresA, mrow0, drow0);
      row_stats_f32<<<2048, b256, 0, stream>>>(scoresB, mrow1, drow1);
      col_mean_f32<<<dim3(8,32), b256, 0, stream>>>(scoresA, mrow0, drow0, wbuf + (r*4+p2*2  )*2048);
      col_mean_f32<<<dim3(8,32), b256, 0, stream>>>(scoresB, mrow1, drow1, wbuf + (r*4+p2*2+1)*2048);
    }
    pooled_par<<<dim3(4,16), b256, 0, stream>>>(qfh, qfl, wbuf + r*8192, pooledB + r*4096);
  }
  pool_ln<<<12, 1024, 0, stream>>>(pooledB, pln_g, pln_b, plbuf);
  init_queries<<<48, b256, 0, stream>>>(pool_b, queries);
  query_accum<<<dim3(12,32), b256, 0, stream>>>(plbuf, pool_w, queries);

  // --- stage D prep (qg weights dead now) + relevance scorer ---
  split_f32_k<<<3072, b256, 0, stream>>>(retr, rh, rl, 786432);
  split_transpose_w<<<dim3(16,32,1), tb, 0, stream>>>(rel_w1, relTh, relTl, 1024, 512);
  init_qpart<<<24, b256, 0, stream>>>(rel_b1, qpart);
  qpart_accum<<<dim3(12,16), b256, 0, stream>>>(queries, rel_w1, qpart);
  gemm_nt_split<SP_QBG_F32,128><<<dim3(4,24,1), b256, 0, stream>>>(
      rh, rl, 1024, 0,  relTh, relTl, 1024, 0,  hbuf, nullptr, 512, 0,  qpart, 1.f, 1024);
  rel_score_f32<<<768, b256, 0, stream>>>(hbuf, rel_w2, rel_b2, relv);

  // --- stage E ---
  select_topk<<<4, 768, 0, stream>>>(relv, selidx, neff, anyv);
  gather_sel<<<dim3(256,4), b256, 0, stream>>>(rh, selidx, neff, seltok);

  // --- stage F ---
  transpose_w<<<dim3(32,32,3), tb, 0, stream>>>(in_w,  inT,  1024, 1024);
  transpose_w<<<dim3(32,32,1), tb, 0, stream>>>(out_w, outT, 1024, 1024);
  gemm_nt<EPI_BIAS,256><<<dim3(8,32,1), b256, 0, stream>>>(
      xh,1024,0,0,  inT,1024,0,0,  qbuf,1024,0,0,  in_b,0, 1.f, 1024, 1);
  gemm_nt<EPI_BIAS,128><<<dim3(8,8,1), b256, 0, stream>>>(
      seltok,1024,0,0,  inT+1048576,1024,0,0,  kbuf,1024,0,0,  in_b+1024,0, 1.f, 1024, 1);
  gemm_nt<EPI_VT,128><<<dim3(8,8,1), b256, 0, stream>>>(
      seltok,1024,0,0,  inT+2097152,1024,0,0,  VT,0,0,0,  in_b+2048,0, 1.f, 1024, 1);
  gemm_nt<EPI_SCALE,128><<<dim3(2,16,32), b256, 0, stream>>>(
      qbuf,1024,2097152,128,  kbuf,1024,262144,128,  Sattn,256,4194304,524288,
      (const float*)nullptr,0, 0.08838834764831845f, 128, 8);
  attn_softmax<<<16384, b256, 0, stream>>>(Sattn, neff);
  gemm_nt<EPI_NONE,128><<<dim3(1,16,32), b256, 0, stream>>>(
      Sattn,256,4194304,524288,  VT,256,262144,32768,  attnout,1024,2097152,128,
      (const float*)nullptr,0, 1.f, 256, 8);
  gemm_nt<EPI_BIAS,256><<<dim3(8,32,1), b256, 0, stream>>>(
      attnout,1024,0,0,  outT,1024,0,0,  fused,1024,0,0,  out_b,0, 1.f, 1024, 1);
  final_ln<<<8192, b256, 0, stream>>>(x, fused, fln_g, fln_b, anyv, out);
}

// Round 7
// 1395.866 us; speedup vs baseline: 1.2375x; 1.2375x over previous
//
#include <hip/hip_runtime.h>
#include <math.h>

// ============================================================================
// RetrievalAugmentedProcessor — MI355X (gfx950)
// B=4 S=2048 D=1024 R=3 K=256 MAXR=256 H=8 HD=128
// R16: R15 post-mortem — counted-vmcnt 3-buf @1 blk/CU still 3.5 TB/s: the
//     drain was never the limit. Evidence across R11/R14/R15/m97: staged
//     delivery scales with RESIDENT WAVES (4w=3.5, 8w=6.5, 12w=14 TB/s) —
//     per-wave DMA issue capacity limits. So: revert to R11 geometry (128^2
//     tile, 512-block grids, 2-deep vmcnt(0) schedule) but 512-THREAD blocks
//     (8 waves): 2 blk/CU -> 16 waves/CU, same traffic, same LDS (64KB x2).
//     Per-thread staging = 1 load_lds16 per array per step; wave-tile 32x64,
//     acc[2][4] (~70 VGPR, launch_bounds(512,4)). Fragment content, MFMA
//     order per output, epilogue unchanged -> bit-identical numerics.
// Layout (MB):  0..24 qgT[A] | 24..40 xh[A,F] | 40..56 xl[A] | 56..72 qfh(r)
//   | 72..88 qfl(r) | 88..120 t1[A scratch, 32MB] / scoresA[B]@88 +
//   scoresB[B]@104 / hbuf[D]@88 / Sattn[F]@88 | 120.. smalls
// Overlays: rh@0 rl@6 relT@12 seltok@14 kbuf@16 VT@18 [D/E] (over dead qgT);
//   inT@40 outT@46 qbuf@56 fused@72 attnout@0 [F]. Peak 120MB <= 131.
// ============================================================================

typedef unsigned short u16;
typedef unsigned int   u32;
typedef __attribute__((ext_vector_type(8))) short short8;   // 8 bf16
typedef __attribute__((ext_vector_type(4))) float f32x4;    // MFMA acc
typedef __attribute__((ext_vector_type(4))) u16  u16x4;

__device__ __forceinline__ float b2f(u16 u){ union{float f;u32 i;} x; x.i=((u32)u)<<16; return x.f; }
__device__ __forceinline__ u16 f2b(float f){ union{float f;u32 i;} x; x.f=f; u32 r=x.i+0x7fffu+((x.i>>16)&1u); return (u16)(r>>16); }
__device__ __forceinline__ float gelu_f(float v){ return 0.5f*v*(1.f+erff(v*0.70710678118654752f)); }

__device__ __forceinline__ void load_lds16(const u16* g, u16* l){
  __builtin_amdgcn_global_load_lds((const __attribute__((address_space(1))) u32*)g,
                                   (__attribute__((address_space(3))) u32*)l, 16, 0, 0);
}

// ---------------- reductions ----------------
__device__ __forceinline__ float waveRedSum(float v){
  #pragma unroll
  for (int o=32;o>0;o>>=1) v += __shfl_xor(v,o);
  return v;
}
__device__ __forceinline__ float waveRedMax(float v){
  #pragma unroll
  for (int o=32;o>0;o>>=1) v = fmaxf(v, __shfl_xor(v,o));
  return v;
}
__device__ float blockRedSum(float v){
  __shared__ float tmp[17];
  const int lane = threadIdx.x&63, wv = threadIdx.x>>6, nw = blockDim.x>>6;
  v = waveRedSum(v);
  __syncthreads();
  if (lane==0) tmp[wv]=v;
  __syncthreads();
  if (threadIdx.x==0){ float s=tmp[0]; for(int i=1;i<nw;i++) s+=tmp[i]; tmp[16]=s; }
  __syncthreads();
  return tmp[16];
}
__device__ float blockRedMax(float v){
  __shared__ float tmp[17];
  const int lane = threadIdx.x&63, wv = threadIdx.x>>6, nw = blockDim.x>>6;
  v = waveRedMax(v);
  __syncthreads();
  if (lane==0) tmp[wv]=v;
  __syncthreads();
  if (threadIdx.x==0){ float s=tmp[0]; for(int i=1;i<nw;i++) s=fmaxf(s,tmp[i]); tmp[16]=s; }
  __syncthreads();
  return tmp[16];
}

// ============================================================================
// Plain bf16 NT GEMM, 512 threads (8 waves), 128x128 tile, 2-deep dbuf.
enum { EPI_NONE=0, EPI_BIAS=1, EPI_SCALE=3, EPI_VT=5 };

template<int EPI>
__global__ __launch_bounds__(512,4)
void gemm_nt(const u16* __restrict__ Ag, long long lda, long long sA1, long long sA2,
             const u16* __restrict__ Bg, long long ldb, long long sB1, long long sB2,
             u16* __restrict__ Cg, long long ldc, long long sC1, long long sC2,
             const float* __restrict__ bias, long long sBias,
             float scale, int K, int H)
{
  __shared__ u16 As[2*4096];
  __shared__ u16 Bs[2*4096];
  const int z  = blockIdx.z;
  const int zb = z / H, zh = z - zb*H;
  const u16* A = Ag + zb*sA1 + zh*sA2;
  const u16* B = Bg + zb*sB1 + zh*sB2;
  const int m0 = blockIdx.y*128, n0 = blockIdx.x*128;
  const int t  = threadIdx.x;
  const int lane = t & 63, wv = t >> 6;
  const int wm = (wv>>1)*32, wn = (wv&1)*64;

  const u16* ga0 = A + (long long)(m0 + (t>>2))*lda + (t&3)*8;
  const u16* gb0 = B + (long long)(n0 + (t>>2))*ldb + (t&3)*8;
  u16* lA0 = As + t*8;
  u16* lB0 = Bs + t*8;

  f32x4 acc[2][4];
  #pragma unroll
  for (int i=0;i<2;i++)
    #pragma unroll
    for (int j=0;j<4;j++) acc[i][j] = (f32x4){0.f,0.f,0.f,0.f};

  const short8* arp = (const short8*)(As + (wm + (lane&15))*32 + ((lane>>4)*8));
  const short8* brp = (const short8*)(Bs + (wn + (lane&15))*32 + ((lane>>4)*8));

  #define STAGE_NT(bo) do{ \
    load_lds16(ga0, lA0+(bo)); \
    load_lds16(gb0, lB0+(bo)); \
    ga0 += 32; gb0 += 32; }while(0)

  const int nk = K >> 5;
  STAGE_NT(0);
  asm volatile("s_waitcnt vmcnt(0)" ::: "memory");
  __builtin_amdgcn_s_barrier();
  int cur = 0;
  for (int kk = 0; kk < nk; ++kk) {
    if (kk+1 < nk) STAGE_NT((cur^1)*4096);
    const int boS = cur*512;   // 4096 u16 = 512 short8
    short8 af[2], bfr[4];
    #pragma unroll
    for (int i=0;i<2;i++) af[i]  = arp[boS + i*64];
    #pragma unroll
    for (int j=0;j<4;j++) bfr[j] = brp[boS + j*64];
    #pragma unroll
    for (int i=0;i<2;i++)
      #pragma unroll
      for (int j=0;j<4;j++)
        acc[i][j] = __builtin_amdgcn_mfma_f32_16x16x32_bf16(af[i], bfr[j], acc[i][j], 0, 0, 0);
    asm volatile("s_waitcnt vmcnt(0)" ::: "memory");
    __builtin_amdgcn_s_barrier();
    cur ^= 1;
  }
  #undef STAGE_NT

  u16* C = Cg + zb*sC1 + zh*sC2;
  const float* bz = bias + zb*sBias;
  const int rb0 = m0 + wm + ((lane>>4)<<2);
  const int cb0 = n0 + wn + (lane&15);
  #pragma unroll
  for (int j=0;j<4;j++){
    const int cn = cb0 + j*16;
    float bv = 0.f;
    if constexpr (EPI==EPI_BIAS || EPI==EPI_VT) bv = bz[cn];
    #pragma unroll
    for (int i=0;i<2;i++){
      #pragma unroll
      for (int p=0;p<4;p++){
        const int row = rb0 + i*16 + p;
        float v = acc[i][j][p];
        if constexpr (EPI==EPI_SCALE) v *= scale;
        if constexpr (EPI==EPI_BIAS)  v += bv;
        if constexpr (EPI==EPI_VT) {
          v += bv;
          const int bb = row>>8, tt = row&255, hh = cn>>7, dd = cn&127;
          C[((long long)((bb*8+hh)*128+dd)<<8) + tt] = f2b(v);
        } else {
          C[(long long)row*ldc + cn] = f2b(v);
        }
      }
    }
  }
}

// ============================================================================
// Split-bf16 NT GEMM: acc += Al*Bh + Ah*Bl + Ah*Bh. 512 threads (8 waves),
// 128x128 tile, 2-deep dbuf. z-batched via sAz/sBz/sCz.
enum { SP_GELU_SPLIT=0, SP_BIAS_SPLIT=1, SP_SCALE_F32=2, SP_QBG_F32=3 };

template<int EPI>
__global__ __launch_bounds__(512,4)
void gemm_nt_split(const u16* __restrict__ Ah_, const u16* __restrict__ Al_, long long lda, long long sAz,
                   const u16* __restrict__ Bh_, const u16* __restrict__ Bl_, long long ldb, long long sBz,
                   void* __restrict__ C0, void* __restrict__ C1, long long ldc, long long sCz,
                   const float* __restrict__ bias, float scale, int K)
{
  __shared__ u16 AsH[2*4096];
  __shared__ u16 AsL[2*4096];
  __shared__ u16 BsH[2*4096];
  __shared__ u16 BsL[2*4096];
  const int z = blockIdx.z;
  const int m0 = blockIdx.y*128, n0 = blockIdx.x*128;
  const int t  = threadIdx.x;
  const int lane = t & 63, wv = t >> 6;
  const int wm = (wv>>1)*32, wn = (wv&1)*64;

  const long long arow = (long long)z*sAz + (long long)(m0 + (t>>2))*lda + (t&3)*8;
  const long long brow = (long long)z*sBz + (long long)(n0 + (t>>2))*ldb + (t&3)*8;
  const u16* gah0 = Ah_ + arow;
  const u16* gal0 = Al_ + arow;
  const u16* gbh0 = Bh_ + brow;
  const u16* gbl0 = Bl_ + brow;
  u16* lAh0 = AsH + t*8;  u16* lAl0 = AsL + t*8;
  u16* lBh0 = BsH + t*8;  u16* lBl0 = BsL + t*8;

  f32x4 acc[2][4];
  #pragma unroll
  for (int i=0;i<2;i++)
    #pragma unroll
    for (int j=0;j<4;j++) acc[i][j] = (f32x4){0.f,0.f,0.f,0.f};

  const int foff = (lane&15)*32 + ((lane>>4)*8);
  const short8* arh = (const short8*)(AsH + wm*32 + foff);
  const short8* arl = (const short8*)(AsL + wm*32 + foff);
  const short8* brh = (const short8*)(BsH + wn*32 + foff);
  const short8* brl = (const short8*)(BsL + wn*32 + foff);

  #define STAGE_SP(bo) do{ \
    load_lds16(gah0, lAh0+(bo)); load_lds16(gal0, lAl0+(bo)); \
    load_lds16(gbh0, lBh0+(bo)); load_lds16(gbl0, lBl0+(bo)); \
    gah0 += 32; gal0 += 32; gbh0 += 32; gbl0 += 32; }while(0)

  const int nk = K >> 5;
  STAGE_SP(0);
  asm volatile("s_waitcnt vmcnt(0)" ::: "memory");
  __builtin_amdgcn_s_barrier();
  int cur = 0;
  for (int kk = 0; kk < nk; ++kk) {
    if (kk+1 < nk) STAGE_SP((cur^1)*4096);
    const int boS = cur*512;   // 4096 u16 = 512 short8
    short8 fah[2], fal[2], fbh[4], fbl[4];
    #pragma unroll
    for (int i=0;i<2;i++){ fah[i]=arh[boS+i*64]; fal[i]=arl[boS+i*64]; }
    #pragma unroll
    for (int j=0;j<4;j++){ fbh[j]=brh[boS+j*64]; fbl[j]=brl[boS+j*64]; }
    #pragma unroll
    for (int i=0;i<2;i++)
      #pragma unroll
      for (int j=0;j<4;j++){
        acc[i][j] = __builtin_amdgcn_mfma_f32_16x16x32_bf16(fal[i], fbh[j], acc[i][j], 0, 0, 0);
        acc[i][j] = __builtin_amdgcn_mfma_f32_16x16x32_bf16(fah[i], fbl[j], acc[i][j], 0, 0, 0);
        acc[i][j] = __builtin_amdgcn_mfma_f32_16x16x32_bf16(fah[i], fbh[j], acc[i][j], 0, 0, 0);
      }
    asm volatile("s_waitcnt vmcnt(0)" ::: "memory");
    __builtin_amdgcn_s_barrier();
    cur ^= 1;
  }
  #undef STAGE_SP

  const int rb0 = m0 + wm + ((lane>>4)<<2);
  const int cb0 = n0 + wn + (lane&15);
  #pragma unroll
  for (int j=0;j<4;j++){
    const int cn = cb0 + j*16;
    float bv = 0.f;
    if constexpr (EPI==SP_GELU_SPLIT || EPI==SP_BIAS_SPLIT) bv = bias[cn];
    #pragma unroll
    for (int i=0;i<2;i++){
      #pragma unroll
      for (int p=0;p<4;p++){
        const int row = rb0 + i*16 + p;
        float v = acc[i][j][p];
        const long long o = (long long)z*sCz + (long long)row*ldc + cn;
        if constexpr (EPI==SP_GELU_SPLIT || EPI==SP_BIAS_SPLIT){
          v += bv;
          if constexpr (EPI==SP_GELU_SPLIT) v = gelu_f(v);
          const u16 h = f2b(v);
          ((u16*)C0)[o] = h;
          ((u16*)C1)[o] = f2b(v - b2f(h));
        }
        if constexpr (EPI==SP_SCALE_F32) ((float*)C0)[o] = v*scale;
        if constexpr (EPI==SP_QBG_F32)   ((float*)C0)[o] = gelu_f(v + bias[(row>>8)*512 + cn]);
      }
    }
  }
}

// ---------------- prep kernels ----------------
__global__ void transpose_w(const float* __restrict__ in, u16* __restrict__ out, int rows, int cols){
  __shared__ float tl[32][33];
  const long long zo = (long long)blockIdx.z*rows*cols;
  const int c0 = blockIdx.x*32, r0 = blockIdx.y*32;
  const int tx = threadIdx.x, ty = threadIdx.y;
  #pragma unroll
  for (int yy=ty; yy<32; yy+=8) tl[yy][tx] = in[zo + (long long)(r0+yy)*cols + (c0+tx)];
  __syncthreads();
  #pragma unroll
  for (int yy=ty; yy<32; yy+=8) out[zo + (long long)(c0+yy)*rows + (r0+tx)] = f2b(tl[tx][yy]);
}

__global__ void split_transpose_w(const float* __restrict__ in, u16* __restrict__ outH,
                                  u16* __restrict__ outL, int rows, int cols){
  __shared__ float tl[32][33];
  const long long zo = (long long)blockIdx.z*rows*cols;
  const int c0 = blockIdx.x*32, r0 = blockIdx.y*32;
  const int tx = threadIdx.x, ty = threadIdx.y;
  #pragma unroll
  for (int yy=ty; yy<32; yy+=8) tl[yy][tx] = in[zo + (long long)(r0+yy)*cols + (c0+tx)];
  __syncthreads();
  #pragma unroll
  for (int yy=ty; yy<32; yy+=8){
    const float v = tl[tx][yy];
    const u16 h = f2b(v);
    const long long o = zo + (long long)(c0+yy)*rows + (r0+tx);
    outH[o] = h;
    outL[o] = f2b(v - b2f(h));
  }
}

__global__ void split_f32_k(const float* __restrict__ in, u16* __restrict__ oh,
                            u16* __restrict__ ol, int n4){
  const int i = blockIdx.x*256 + threadIdx.x;
  if (i < n4){
    const float4 v = ((const float4*)in)[i];
    u16x4 hh, ll;
    hh.x=f2b(v.x); ll.x=f2b(v.x-b2f(hh.x));
    hh.y=f2b(v.y); ll.y=f2b(v.y-b2f(hh.y));
    hh.z=f2b(v.z); ll.z=f2b(v.z-b2f(hh.z));
    hh.w=f2b(v.w); ll.w=f2b(v.w-b2f(hh.w));
    ((u16x4*)oh)[i] = hh;
    ((u16x4*)ol)[i] = ll;
  }
}

__global__ void zero_f32(float* __restrict__ p, int n){
  const int i = blockIdx.x*256 + threadIdx.x;
  if (i < n) p[i] = 0.f;
}

__global__ void init_queries(const float* __restrict__ pb, float* __restrict__ q){
  const int i = blockIdx.x*256 + threadIdx.x;
  if (i < 12288) q[i] = pb[(i>>12)*1024 + (i&1023)];
}
__global__ void init_qpart(const float* __restrict__ rb1, float* __restrict__ qp){
  const int i = blockIdx.x*256 + threadIdx.x;
  if (i < 6144) qp[i] = rb1[i&511];
}

__global__ void ws_report(float* __restrict__ out, int n4, float val){
  const int i = blockIdx.x*256 + threadIdx.x;
  if (i < n4){
    float4 z; z.x = (i==0)? val : 0.f; z.y=0.f; z.z=0.f; z.w=0.f;
    ((float4*)out)[i] = z;
  }
}

// ---------------- pooling (fp32 scores) ----------------
__global__ void row_stats_f32(const float* __restrict__ S, float* __restrict__ mOut,
                              float* __restrict__ dOut){
  const int row = blockIdx.x;
  const float4* p = (const float4*)(S + (long long)row*2048);
  const int tid = threadIdx.x;
  const float4 a = p[2*tid], b = p[2*tid+1];
  float v[8] = {a.x,a.y,a.z,a.w,b.x,b.y,b.z,b.w};
  float mx = v[0];
  #pragma unroll
  for (int k=1;k<8;k++) mx = fmaxf(mx, v[k]);
  mx = blockRedMax(mx);
  float s = 0.f;
  #pragma unroll
  for (int k=0;k<8;k++) s += expf(v[k]-mx);
  s = blockRedSum(s);
  if (tid==0){ mOut[row]=mx; dOut[row]=s; }
}

__global__ void col_mean_f32(const float* __restrict__ S, const float* __restrict__ m,
                             const float* __restrict__ den, float* __restrict__ w){
  const int tc = blockIdx.x*256 + threadIdx.x;
  const int s0 = blockIdx.y*64;
  const float* p = S + (long long)s0*2048 + tc;
  float acc = 0.f;
  for (int s=0;s<64;s++)
    acc += expf(p[(long long)s<<11] - m[s0+s]) * (1.0f/den[s0+s]);
  atomicAdd(&w[tc], acc * (1.f/2048.f));
}

// pooled[b][d] += tile sums; grid (4,16) per retriever (R6-proven)
__global__ __launch_bounds__(256)
void pooled_par(const u16* __restrict__ qfh, const u16* __restrict__ qfl,
                const float* __restrict__ w, float* __restrict__ pooled){
  const int b = blockIdx.x, tt0 = blockIdx.y*128;
  const int t = threadIdx.x;
  __shared__ float wsh[128];
  if (t < 128) wsh[t] = w[b*2048 + tt0 + t];
  __syncthreads();
  const long long base = (long long)b*2097152 + (long long)tt0*1024;
  const u16* ph = qfh + base;
  const u16* pl = qfl + base;
  float acc[4] = {0.f,0.f,0.f,0.f};
  for (int s=0; s<128; s++){
    const float wt = wsh[s];
    const long long o = (long long)s*1024;
    #pragma unroll
    for (int k=0;k<4;k++){
      const int dd = t + k*256;
      acc[k] += wt*(b2f(ph[o+dd]) + b2f(pl[o+dd]));
    }
  }
  #pragma unroll
  for (int k=0;k<4;k++) atomicAdd(&pooled[b*1024 + t + k*256], acc[k]);
}

__global__ __launch_bounds__(1024)
void pool_ln(const float* __restrict__ pooled, const float* __restrict__ pg,
             const float* __restrict__ pb, float* __restrict__ plbuf){
  const int z = blockIdx.x, r = z>>2, d = threadIdx.x;
  const float v = pooled[z*1024+d];
  const float mean = blockRedSum(v) * (1.f/1024.f);
  const float df = v - mean;
  const float var = blockRedSum(df*df) * (1.f/1024.f);
  plbuf[z*1024+d] = df*rsqrtf(var+1e-5f)*pg[r*1024+d] + pb[r*1024+d];
}

__global__ __launch_bounds__(256)
void query_accum(const float* __restrict__ plbuf, const float* __restrict__ pw,
                 float* __restrict__ queries){
  const int z = blockIdx.x, r = z>>2, k0 = blockIdx.y*32;
  const int t = threadIdx.x;
  __shared__ float pls[32];
  if (t < 32) pls[t] = plbuf[z*1024 + k0 + t];
  __syncthreads();
  const float* wp = pw + (long long)r*1048576 + (long long)k0*1024;
  float acc[4] = {0.f,0.f,0.f,0.f};
  for (int s=0;s<32;s++){
    const float wv = pls[s];
    #pragma unroll
    for (int c=0;c<4;c++) acc[c] += wv*wp[s*1024 + t + c*256];
  }
  #pragma unroll
  for (int c=0;c<4;c++) atomicAdd(&queries[z*1024 + t + c*256], acc[c]);
}

__global__ __launch_bounds__(256)
void qpart_accum(const float* __restrict__ queries, const float* __restrict__ rw1,
                 float* __restrict__ qpart){
  const int z = blockIdx.x, k0 = blockIdx.y*64;
  const int t = threadIdx.x;
  __shared__ float qs[64];
  if (t < 64) qs[t] = queries[z*1024 + k0 + t];
  __syncthreads();
  const float* wp = rw1 + 1024*512 + (long long)k0*512;
  float acc[2] = {0.f,0.f};
  for (int s=0;s<64;s++){
    const float wv = qs[s];
    #pragma unroll
    for (int c=0;c<2;c++) acc[c] += wv*wp[s*512 + t + c*256];
  }
  #pragma unroll
  for (int c=0;c<2;c++) atomicAdd(&qpart[z*512 + t + c*256], acc[c]);
}

__global__ void rel_score_f32(const float* __restrict__ h, const float* __restrict__ w2,
                              const float* __restrict__ b2p, float* __restrict__ relv){
  const int row = blockIdx.x*4 + (threadIdx.x>>6);
  const int lane = threadIdx.x & 63;
  const float* p = h + (long long)row*512;
  float a = 0.f;
  #pragma unroll
  for (int k=0;k<8;k++){ const int idx = lane + k*64; a += p[idx]*w2[idx]; }
  a = waveRedSum(a);
  if (lane==0){
    const float lg = a + b2p[0];
    relv[row] = 1.f/(1.f+expf(-lg));
  }
}

// ---------------- selection ----------------
__global__ __launch_bounds__(768)
void select_topk(const float* __restrict__ relv, int* __restrict__ selidx,
                 int* __restrict__ neff, int* __restrict__ anyv){
  const int b = blockIdx.x, c = threadIdx.x;
  __shared__ float rv[768];
  __shared__ int cnt;
  rv[c] = relv[(((c>>8)*4)+b)*256 + (c&255)];
  if (c==0) cnt = 0;
  __syncthreads();
  const float mine = rv[c];
  const bool valid = (mine >= 0.5f);
  int rank = 0;
  for (int j=0;j<768;j++){
    const float vj = rv[j];
    if (vj >= 0.5f && (vj > mine || (vj == mine && j < c))) rank++;
  }
  if (valid && rank < 256){
    const int s = atomicAdd(&cnt, 1);
    selidx[b*256 + s] = c;
  }
  __syncthreads();
  if (c==0){ neff[b] = cnt; anyv[b] = (cnt>0) ? 1 : 0; }
}

__global__ void gather_sel(const u16* __restrict__ rb16, const int* __restrict__ selidx,
                           const int* __restrict__ neff, u16* __restrict__ seltok){
  const int slot = blockIdx.x, b = blockIdx.y, tid = threadIdx.x;
  uint2 val; val.x=0u; val.y=0u;
  if (slot < neff[b]){
    const int c = selidx[b*256+slot];
    const uint2* src = (const uint2*)(rb16 + (long long)(((c>>8)*4+b)*256 + (c&255))*1024);
    val = src[tid];
  }
  ((uint2*)(seltok + (long long)(b*256+slot)*1024))[tid] = val;
}

__global__ void attn_softmax(u16* __restrict__ S, const int* __restrict__ neff){
  const int ri = blockIdx.x*4 + (threadIdx.x>>6);
  const int lane = threadIdx.x & 63;
  const int b = ri >> 14;
  const int ne = neff[b];
  u16* p = S + (long long)ri*256 + lane*4;
  if (ne == 0){ uint2 zz; zz.x=0u; zz.y=0u; *(uint2*)p = zz; return; }
  uint2 raw = *(const uint2*)p;
  u16 uu[4] = {(u16)(raw.x&0xffffu),(u16)(raw.x>>16),(u16)(raw.y&0xffffu),(u16)(raw.y>>16)};
  float xs[4];
  #pragma unroll
  for (int q2=0;q2<4;q2++){ const int tt = lane*4+q2; xs[q2] = (tt<ne)? b2f(uu[q2]) : -1e30f; }
  float mx = fmaxf(fmaxf(xs[0],xs[1]),fmaxf(xs[2],xs[3]));
  mx = waveRedMax(mx);
  float e[4]; float sm=0.f;
  #pragma unroll
  for (int q2=0;q2<4;q2++){ e[q2] = (lane*4+q2<ne)? expf(xs[q2]-mx) : 0.f; sm += e[q2]; }
  sm = waveRedSum(sm);
  const float inv = 1.f/sm;
  #pragma unroll
  for (int q2=0;q2<4;q2++) uu[q2] = f2b(e[q2]*inv);
  raw.x = (u32)uu[0] | ((u32)uu[1]<<16);
  raw.y = (u32)uu[2] | ((u32)uu[3]<<16);
  *(uint2*)p = raw;
}

__global__ void final_ln(const float* __restrict__ x, const u16* __restrict__ fused,
                         const float* __restrict__ g, const float* __restrict__ bb,
                         const int* __restrict__ anyv, float* __restrict__ out){
  const int row = blockIdx.x; const int b = row>>11; const int tid = threadIdx.x;
  const float4 xv = ((const float4*)(x + (long long)row*1024))[tid];
  const uint2 fv = ((const uint2*)(fused + (long long)row*1024))[tid];
  const float e0 = xv.x + b2f((u16)(fv.x&0xffffu));
  const float e1 = xv.y + b2f((u16)(fv.x>>16));
  const float e2 = xv.z + b2f((u16)(fv.y&0xffffu));
  const float e3 = xv.w + b2f((u16)(fv.y>>16));
  const float mean = blockRedSum(e0+e1+e2+e3) * (1.f/1024.f);
  const float d0=e0-mean, d1=e1-mean, d2=e2-mean, d3=e3-mean;
  const float var = blockRedSum(d0*d0+d1*d1+d2*d2+d3*d3) * (1.f/1024.f);
  const float inv = rsqrtf(var + 1e-5f);
  const float4 gv = ((const float4*)g)[tid];
  const float4 bv = ((const float4*)bb)[tid];
  float4 o;
  if (anyv[b]){
    o.x = d0*inv*gv.x + bv.x; o.y = d1*inv*gv.y + bv.y;
    o.z = d2*inv*gv.z + bv.z; o.w = d3*inv*gv.w + bv.w;
  } else o = xv;
  ((float4*)(out + (long long)row*1024))[tid] = o;
}

// ============================================================================
extern "C" void kernel_launch(void* const* d_in, const int* in_sizes, int n_in,
                              void* d_out, int out_size, void* d_ws, size_t ws_size,
                              hipStream_t stream) {
  (void)in_sizes; (void)n_in;
  const float* x      = (const float*)d_in[0];
  const float* retr   = (const float*)d_in[1];
  const float* qg_w1  = (const float*)d_in[2];
  const float* qg_b1  = (const float*)d_in[3];
  const float* qg_w2  = (const float*)d_in[4];
  const float* qg_b2  = (const float*)d_in[5];
  const float* pln_g  = (const float*)d_in[6];
  const float* pln_b  = (const float*)d_in[7];
  const float* pool_w = (const float*)d_in[8];
  const float* pool_b = (const float*)d_in[9];
  const float* rel_w1 = (const float*)d_in[10];
  const float* rel_b1 = (const float*)d_in[11];
  const float* rel_w2 = (const float*)d_in[12];
  const float* rel_b2 = (const float*)d_in[13];
  const float* in_w   = (const float*)d_in[14];
  const float* in_b   = (const float*)d_in[15];
  const float* out_w  = (const float*)d_in[16];
  const float* out_b  = (const float*)d_in[17];
  const float* fln_g  = (const float*)d_in[18];
  const float* fln_b  = (const float*)d_in[19];
  float* out = (float*)d_out;
  char* ws = (char*)d_ws;

  const size_t MB = 1u<<20;
  const size_t REQUIRED = 131*MB;
  if (ws_size < REQUIRED){
    ws_report<<<(out_size/4 + 255)/256, 256, 0, stream>>>(out, out_size/4, (float)(ws_size>>20));
    return;
  }

  // ---- layout per header comment ----
  u16* qg1Th = (u16*)(ws + 0*MB);        // [P->A]
  u16* qg1Tl = (u16*)(ws + 6*MB);
  u16* qg2Th = (u16*)(ws + 12*MB);
  u16* qg2Tl = (u16*)(ws + 18*MB);
  u16* xh    = (u16*)(ws + 24*MB);       // [P->A,F]
  u16* xl    = (u16*)(ws + 40*MB);       // [P->A]
  u16* qfh   = (u16*)(ws + 56*MB);       // per-retriever [A->B]
  u16* qfl   = (u16*)(ws + 72*MB);
  u16* t1h   = (u16*)(ws + 88*MB);       // [A scratch]
  u16* t1l   = (u16*)(ws + 104*MB);      // [A scratch]
  float* scoresA = (float*)(ws + 88*MB); // [B] over dead t1h
  float* scoresB = (float*)(ws + 104*MB);// [B] over dead t1l
  // stage D/E overlays (qg weights dead after stage A):
  u16* rh    = (u16*)(ws + 0*MB);        // 6  [D,E]
  u16* rl    = (u16*)(ws + 6*MB);        // 6  [D]
  u16* relTh = (u16*)(ws + 12*MB);       // 1  [D]
  u16* relTl = (u16*)(ws + 13*MB);       // 1  [D]
  u16* seltok= (u16*)(ws + 14*MB);       // 2  [E->F vproj]
  u16* kbuf  = (u16*)(ws + 16*MB);       // 2  [F, dead after QK^T]
  u16* VT    = (u16*)(ws + 18*MB);       // 2  [F, dead after AV]
  float* hbuf= (float*)(ws + 88*MB);     // 6  [D] over dead scoresA
  // stage F overlays:
  u16* inT   = (u16*)(ws + 40*MB);       // 6  over dead xl
  u16* outT  = (u16*)(ws + 46*MB);       // 2
  u16* qbuf  = (u16*)(ws + 56*MB);       // 16 over dead qfh
  u16* fused = (u16*)(ws + 72*MB);       // 16 over dead qfl
  u16* Sattn = (u16*)(ws + 88*MB);       // 32 over dead scores
  u16* attnout=(u16*)(ws + 0*MB);        // 16 over dead rh/rl/relT/seltok
  char* SM = ws + 120*MB;
  float* wbuf    = (float*)(SM);            // 96 KB [12][2048]
  float* pooledB = (float*)(SM + 98304);    // 48 KB
  float* plbuf   = (float*)(SM + 147456);   // 48 KB
  float* queries = (float*)(SM + 196608);   // 48 KB
  float* qpart   = (float*)(SM + 245760);   // 24 KB
  float* relv    = (float*)(SM + 270336);   // 12 KB
  int*   selidx  = (int*)(SM + 282624);
  int*   neff    = (int*)(SM + 286720);
  int*   anyv    = (int*)(SM + 286784);
  float* mrow0   = (float*)(SM + 286848);
  float* drow0   = (float*)(SM + 295040);
  float* mrow1   = (float*)(SM + 303232);
  float* drow1   = (float*)(SM + 311424);

  dim3 b256(256);
  dim3 b512(512);
  dim3 tb(32,8);
  const long long SCZ = (long long)(16*MB)/4;   // scoresA -> scoresB (4,194,304 floats)

  // --- prep ---
  split_transpose_w<<<dim3(32,32,3), tb, 0, stream>>>(qg_w1, qg1Th, qg1Tl, 1024, 1024);
  split_transpose_w<<<dim3(32,32,3), tb, 0, stream>>>(qg_w2, qg2Th, qg2Tl, 1024, 1024);
  split_f32_k<<<8192, b256, 0, stream>>>(x, xh, xl, 2097152);
  zero_f32<<<144, b256, 0, stream>>>(wbuf, 36864);   // wbuf + pooledB

  // --- stages A+B interleaved per retriever (128^2 tiles, 512-thr blocks) ---
  for (int r = 0; r < 3; r++){
    const long long wo = (long long)r*1048576;
    gemm_nt_split<SP_GELU_SPLIT><<<dim3(8,64,1), b512, 0, stream>>>(
        xh, xl, 1024, 0,  qg1Th+wo, qg1Tl+wo, 1024, 0,
        t1h, t1l, 1024, 0,  qg_b1+r*1024, 1.f, 1024);
    gemm_nt_split<SP_BIAS_SPLIT><<<dim3(8,64,1), b512, 0, stream>>>(
        t1h, t1l, 1024, 0,  qg2Th+wo, qg2Tl+wo, 1024, 0,
        qfh, qfl, 1024, 0,  qg_b2+r*1024, 1.f, 1024);
    for (int p2 = 0; p2 < 2; p2++){
      const long long qo = (long long)(p2*2)*2097152;
      gemm_nt_split<SP_SCALE_F32><<<dim3(16,16,2), b512, 0, stream>>>(
          qfh+qo, qfl+qo, 1024, 2097152,  qfh+qo, qfl+qo, 1024, 2097152,
          scoresA, nullptr, 2048, SCZ,  nullptr, 0.03125f, 1024);
      row_stats_f32<<<2048, b256, 0, stream>>>(scoresA, mrow0, drow0);
      row_stats_f32<<<2048, b256, 0, stream>>>(scoresB, mrow1, drow1);
      col_mean_f32<<<dim3(8,32), b256, 0, stream>>>(scoresA, mrow0, drow0, wbuf + (r*4+p2*2  )*2048);
      col_mean_f32<<<dim3(8,32), b256, 0, stream>>>(scoresB, mrow1, drow1, wbuf + (r*4+p2*2+1)*2048);
    }
    pooled_par<<<dim3(4,16), b256, 0, stream>>>(qfh, qfl, wbuf + r*8192, pooledB + r*4096);
  }
  pool_ln<<<12, 1024, 0, stream>>>(pooledB, pln_g, pln_b, plbuf);
  init_queries<<<48, b256, 0, stream>>>(pool_b, queries);
  query_accum<<<dim3(12,32), b256, 0, stream>>>(plbuf, pool_w, queries);

  // --- stage D prep (qg weights dead now) + relevance scorer ---
  split_f32_k<<<3072, b256, 0, stream>>>(retr, rh, rl, 786432);
  split_transpose_w<<<dim3(16,32,1), tb, 0, stream>>>(rel_w1, relTh, relTl, 1024, 512);
  init_qpart<<<24, b256, 0, stream>>>(rel_b1, qpart);
  qpart_accum<<<dim3(12,16), b256, 0, stream>>>(queries, rel_w1, qpart);
  gemm_nt_split<SP_QBG_F32><<<dim3(4,24,1), b512, 0, stream>>>(
      rh, rl, 1024, 0,  relTh, relTl, 1024, 0,  hbuf, nullptr, 512, 0,  qpart, 1.f, 1024);
  rel_score_f32<<<768, b256, 0, stream>>>(hbuf, rel_w2, rel_b2, relv);

  // --- stage E ---
  select_topk<<<4, 768, 0, stream>>>(relv, selidx, neff, anyv);
  gather_sel<<<dim3(256,4), b256, 0, stream>>>(rh, selidx, neff, seltok);

  // --- stage F ---
  transpose_w<<<dim3(32,32,3), tb, 0, stream>>>(in_w,  inT,  1024, 1024);
  transpose_w<<<dim3(32,32,1), tb, 0, stream>>>(out_w, outT, 1024, 1024);
  gemm_nt<EPI_BIAS><<<dim3(8,64,1), b512, 0, stream>>>(
      xh,1024,0,0,  inT,1024,0,0,  qbuf,1024,0,0,  in_b,0, 1.f, 1024, 1);
  gemm_nt<EPI_BIAS><<<dim3(8,8,1), b512, 0, stream>>>(
      seltok,1024,0,0,  inT+1048576,1024,0,0,  kbuf,1024,0,0,  in_b+1024,0, 1.f, 1024, 1);
  gemm_nt<EPI_VT><<<dim3(8,8,1), b512, 0, stream>>>(
      seltok,1024,0,0,  inT+2097152,1024,0,0,  VT,0,0,0,  in_b+2048,0, 1.f, 1024, 1);
  gemm_nt<EPI_SCALE><<<dim3(2,16,32), b512, 0, stream>>>(
      qbuf,1024,2097152,128,  kbuf,1024,262144,128,  Sattn,256,4194304,524288,
      (const float*)nullptr,0, 0.08838834764831845f, 128, 8);
  attn_softmax<<<16384, b256, 0, stream>>>(Sattn, neff);
  gemm_nt<EPI_NONE><<<dim3(1,16,32), b512, 0, stream>>>(
      Sattn,256,4194304,524288,  VT,256,262144,32768,  attnout,1024,2097152,128,
      (const float*)nullptr,0, 1.f, 256, 8);
  gemm_nt<EPI_BIAS><<<dim3(8,64,1), b512, 0, stream>>>(
      attnout,1024,0,0,  outT,1024,0,0,  fused,1024,0,0,  out_b,0, 1.f, 1024, 1);
  final_ln<<<8192, b256, 0, stream>>>(x, fused, fln_g, fln_b, anyv, out);
}

// Round 8
// 1296.701 us; speedup vs baseline: 1.3321x; 1.0765x over previous
//
#include <hip/hip_runtime.h>
#include <math.h>

// ============================================================================
// RetrievalAugmentedProcessor — MI355X (gfx950)
// B=4 S=2048 D=1024 R=3 K=256 MAXR=256 H=8 HD=128
// R17: R16 (512-thr, 16 waves/CU, 7.5 TB/s staged) confirmed the GEMM plateau
//     (~12.2 B/cyc/CU delivery; tile geometry is scale-invariant; more waves
//     impossible at BK=32 LDS). R17 harvests the stats tail: the score GEMM
//     epilogue now emits per-(row, 64col-group) partial (max, expsum) pairs
//     (values are in registers anyway); a tiny merge_stats kernel combines 32
//     partials/row via exact log-sum-exp merge. Removes all 12 row_stats
//     launches (192 MB of S re-reads); col_mean A/B fused into z=2 launches
//     (12->6). GEMM kernels bit-identical to R16.
// Layout (MB):  0..24 qgT[A] | 24..40 xh[A,F] | 40..56 xl[A] | 56..72 qfh(r)
//   | 72..88 qfl(r) | 88..120 t1[A scratch] / scoresA[B]@88 + scoresB[B]@104
//   / hbuf[D]@88 / Sattn[F]@88 | 120.. smalls (+partM@.5MB, partS@1MB)
// Overlays: rh@0 rl@6 relT@12 seltok@14 kbuf@16 VT@18 [D/E] (over dead qgT);
//   inT@40 outT@46 qbuf@56 fused@72 attnout@0 [F]. Peak 120MB <= 131.
// ============================================================================

typedef unsigned short u16;
typedef unsigned int   u32;
typedef __attribute__((ext_vector_type(8))) short short8;   // 8 bf16
typedef __attribute__((ext_vector_type(4))) float f32x4;    // MFMA acc
typedef __attribute__((ext_vector_type(4))) u16  u16x4;

__device__ __forceinline__ float b2f(u16 u){ union{float f;u32 i;} x; x.i=((u32)u)<<16; return x.f; }
__device__ __forceinline__ u16 f2b(float f){ union{float f;u32 i;} x; x.f=f; u32 r=x.i+0x7fffu+((x.i>>16)&1u); return (u16)(r>>16); }
__device__ __forceinline__ float gelu_f(float v){ return 0.5f*v*(1.f+erff(v*0.70710678118654752f)); }

__device__ __forceinline__ void load_lds16(const u16* g, u16* l){
  __builtin_amdgcn_global_load_lds((const __attribute__((address_space(1))) u32*)g,
                                   (__attribute__((address_space(3))) u32*)l, 16, 0, 0);
}

// ---------------- reductions ----------------
__device__ __forceinline__ float waveRedSum(float v){
  #pragma unroll
  for (int o=32;o>0;o>>=1) v += __shfl_xor(v,o);
  return v;
}
__device__ __forceinline__ float waveRedMax(float v){
  #pragma unroll
  for (int o=32;o>0;o>>=1) v = fmaxf(v, __shfl_xor(v,o));
  return v;
}
__device__ float blockRedSum(float v){
  __shared__ float tmp[17];
  const int lane = threadIdx.x&63, wv = threadIdx.x>>6, nw = blockDim.x>>6;
  v = waveRedSum(v);
  __syncthreads();
  if (lane==0) tmp[wv]=v;
  __syncthreads();
  if (threadIdx.x==0){ float s=tmp[0]; for(int i=1;i<nw;i++) s+=tmp[i]; tmp[16]=s; }
  __syncthreads();
  return tmp[16];
}
__device__ float blockRedMax(float v){
  __shared__ float tmp[17];
  const int lane = threadIdx.x&63, wv = threadIdx.x>>6, nw = blockDim.x>>6;
  v = waveRedMax(v);
  __syncthreads();
  if (lane==0) tmp[wv]=v;
  __syncthreads();
  if (threadIdx.x==0){ float s=tmp[0]; for(int i=1;i<nw;i++) s=fmaxf(s,tmp[i]); tmp[16]=s; }
  __syncthreads();
  return tmp[16];
}

// ============================================================================
// Plain bf16 NT GEMM, 512 threads (8 waves), 128x128 tile, 2-deep dbuf.
enum { EPI_NONE=0, EPI_BIAS=1, EPI_SCALE=3, EPI_VT=5 };

template<int EPI>
__global__ __launch_bounds__(512,4)
void gemm_nt(const u16* __restrict__ Ag, long long lda, long long sA1, long long sA2,
             const u16* __restrict__ Bg, long long ldb, long long sB1, long long sB2,
             u16* __restrict__ Cg, long long ldc, long long sC1, long long sC2,
             const float* __restrict__ bias, long long sBias,
             float scale, int K, int H)
{
  __shared__ u16 As[2*4096];
  __shared__ u16 Bs[2*4096];
  const int z  = blockIdx.z;
  const int zb = z / H, zh = z - zb*H;
  const u16* A = Ag + zb*sA1 + zh*sA2;
  const u16* B = Bg + zb*sB1 + zh*sB2;
  const int m0 = blockIdx.y*128, n0 = blockIdx.x*128;
  const int t  = threadIdx.x;
  const int lane = t & 63, wv = t >> 6;
  const int wm = (wv>>1)*32, wn = (wv&1)*64;

  const u16* ga0 = A + (long long)(m0 + (t>>2))*lda + (t&3)*8;
  const u16* gb0 = B + (long long)(n0 + (t>>2))*ldb + (t&3)*8;
  u16* lA0 = As + t*8;
  u16* lB0 = Bs + t*8;

  f32x4 acc[2][4];
  #pragma unroll
  for (int i=0;i<2;i++)
    #pragma unroll
    for (int j=0;j<4;j++) acc[i][j] = (f32x4){0.f,0.f,0.f,0.f};

  const short8* arp = (const short8*)(As + (wm + (lane&15))*32 + ((lane>>4)*8));
  const short8* brp = (const short8*)(Bs + (wn + (lane&15))*32 + ((lane>>4)*8));

  #define STAGE_NT(bo) do{ \
    load_lds16(ga0, lA0+(bo)); \
    load_lds16(gb0, lB0+(bo)); \
    ga0 += 32; gb0 += 32; }while(0)

  const int nk = K >> 5;
  STAGE_NT(0);
  asm volatile("s_waitcnt vmcnt(0)" ::: "memory");
  __builtin_amdgcn_s_barrier();
  int cur = 0;
  for (int kk = 0; kk < nk; ++kk) {
    if (kk+1 < nk) STAGE_NT((cur^1)*4096);
    const int boS = cur*512;   // 4096 u16 = 512 short8
    short8 af[2], bfr[4];
    #pragma unroll
    for (int i=0;i<2;i++) af[i]  = arp[boS + i*64];
    #pragma unroll
    for (int j=0;j<4;j++) bfr[j] = brp[boS + j*64];
    #pragma unroll
    for (int i=0;i<2;i++)
      #pragma unroll
      for (int j=0;j<4;j++)
        acc[i][j] = __builtin_amdgcn_mfma_f32_16x16x32_bf16(af[i], bfr[j], acc[i][j], 0, 0, 0);
    asm volatile("s_waitcnt vmcnt(0)" ::: "memory");
    __builtin_amdgcn_s_barrier();
    cur ^= 1;
  }
  #undef STAGE_NT

  u16* C = Cg + zb*sC1 + zh*sC2;
  const float* bz = bias + zb*sBias;
  const int rb0 = m0 + wm + ((lane>>4)<<2);
  const int cb0 = n0 + wn + (lane&15);
  #pragma unroll
  for (int j=0;j<4;j++){
    const int cn = cb0 + j*16;
    float bv = 0.f;
    if constexpr (EPI==EPI_BIAS || EPI==EPI_VT) bv = bz[cn];
    #pragma unroll
    for (int i=0;i<2;i++){
      #pragma unroll
      for (int p=0;p<4;p++){
        const int row = rb0 + i*16 + p;
        float v = acc[i][j][p];
        if constexpr (EPI==EPI_SCALE) v *= scale;
        if constexpr (EPI==EPI_BIAS)  v += bv;
        if constexpr (EPI==EPI_VT) {
          v += bv;
          const int bb = row>>8, tt = row&255, hh = cn>>7, dd = cn&127;
          C[((long long)((bb*8+hh)*128+dd)<<8) + tt] = f2b(v);
        } else {
          C[(long long)row*ldc + cn] = f2b(v);
        }
      }
    }
  }
}

// ============================================================================
// Split-bf16 NT GEMM: acc += Al*Bh + Ah*Bl + Ah*Bh. 512 threads (8 waves),
// 128x128 tile, 2-deep dbuf. z-batched via sAz/sBz/sCz.
// SP_SCALE_STATS: score epilogue also emits per-(row, 64col-group) partial
// (max, expsum) pairs -> pm/ps [(z*2048+row)*32 + g], g = bx*2 + (wv&1).
enum { SP_GELU_SPLIT=0, SP_BIAS_SPLIT=1, SP_SCALE_F32=2, SP_QBG_F32=3, SP_SCALE_STATS=4 };

template<int EPI>
__global__ __launch_bounds__(512,4)
void gemm_nt_split(const u16* __restrict__ Ah_, const u16* __restrict__ Al_, long long lda, long long sAz,
                   const u16* __restrict__ Bh_, const u16* __restrict__ Bl_, long long ldb, long long sBz,
                   void* __restrict__ C0, void* __restrict__ C1, long long ldc, long long sCz,
                   const float* __restrict__ bias, float scale, int K,
                   float* __restrict__ pm, float* __restrict__ ps)
{
  __shared__ u16 AsH[2*4096];
  __shared__ u16 AsL[2*4096];
  __shared__ u16 BsH[2*4096];
  __shared__ u16 BsL[2*4096];
  const int z = blockIdx.z;
  const int m0 = blockIdx.y*128, n0 = blockIdx.x*128;
  const int t  = threadIdx.x;
  const int lane = t & 63, wv = t >> 6;
  const int wm = (wv>>1)*32, wn = (wv&1)*64;

  const long long arow = (long long)z*sAz + (long long)(m0 + (t>>2))*lda + (t&3)*8;
  const long long brow = (long long)z*sBz + (long long)(n0 + (t>>2))*ldb + (t&3)*8;
  const u16* gah0 = Ah_ + arow;
  const u16* gal0 = Al_ + arow;
  const u16* gbh0 = Bh_ + brow;
  const u16* gbl0 = Bl_ + brow;
  u16* lAh0 = AsH + t*8;  u16* lAl0 = AsL + t*8;
  u16* lBh0 = BsH + t*8;  u16* lBl0 = BsL + t*8;

  f32x4 acc[2][4];
  #pragma unroll
  for (int i=0;i<2;i++)
    #pragma unroll
    for (int j=0;j<4;j++) acc[i][j] = (f32x4){0.f,0.f,0.f,0.f};

  const int foff = (lane&15)*32 + ((lane>>4)*8);
  const short8* arh = (const short8*)(AsH + wm*32 + foff);
  const short8* arl = (const short8*)(AsL + wm*32 + foff);
  const short8* brh = (const short8*)(BsH + wn*32 + foff);
  const short8* brl = (const short8*)(BsL + wn*32 + foff);

  #define STAGE_SP(bo) do{ \
    load_lds16(gah0, lAh0+(bo)); load_lds16(gal0, lAl0+(bo)); \
    load_lds16(gbh0, lBh0+(bo)); load_lds16(gbl0, lBl0+(bo)); \
    gah0 += 32; gal0 += 32; gbh0 += 32; gbl0 += 32; }while(0)

  const int nk = K >> 5;
  STAGE_SP(0);
  asm volatile("s_waitcnt vmcnt(0)" ::: "memory");
  __builtin_amdgcn_s_barrier();
  int cur = 0;
  for (int kk = 0; kk < nk; ++kk) {
    if (kk+1 < nk) STAGE_SP((cur^1)*4096);
    const int boS = cur*512;   // 4096 u16 = 512 short8
    short8 fah[2], fal[2], fbh[4], fbl[4];
    #pragma unroll
    for (int i=0;i<2;i++){ fah[i]=arh[boS+i*64]; fal[i]=arl[boS+i*64]; }
    #pragma unroll
    for (int j=0;j<4;j++){ fbh[j]=brh[boS+j*64]; fbl[j]=brl[boS+j*64]; }
    #pragma unroll
    for (int i=0;i<2;i++)
      #pragma unroll
      for (int j=0;j<4;j++){
        acc[i][j] = __builtin_amdgcn_mfma_f32_16x16x32_bf16(fal[i], fbh[j], acc[i][j], 0, 0, 0);
        acc[i][j] = __builtin_amdgcn_mfma_f32_16x16x32_bf16(fah[i], fbl[j], acc[i][j], 0, 0, 0);
        acc[i][j] = __builtin_amdgcn_mfma_f32_16x16x32_bf16(fah[i], fbh[j], acc[i][j], 0, 0, 0);
      }
    asm volatile("s_waitcnt vmcnt(0)" ::: "memory");
    __builtin_amdgcn_s_barrier();
    cur ^= 1;
  }
  #undef STAGE_SP

  const int rb0 = m0 + wm + ((lane>>4)<<2);
  const int cb0 = n0 + wn + (lane&15);
  #pragma unroll
  for (int j=0;j<4;j++){
    const int cn = cb0 + j*16;
    float bv = 0.f;
    if constexpr (EPI==SP_GELU_SPLIT || EPI==SP_BIAS_SPLIT) bv = bias[cn];
    #pragma unroll
    for (int i=0;i<2;i++){
      #pragma unroll
      for (int p=0;p<4;p++){
        const int row = rb0 + i*16 + p;
        float v = acc[i][j][p];
        const long long o = (long long)z*sCz + (long long)row*ldc + cn;
        if constexpr (EPI==SP_GELU_SPLIT || EPI==SP_BIAS_SPLIT){
          v += bv;
          if constexpr (EPI==SP_GELU_SPLIT) v = gelu_f(v);
          const u16 h = f2b(v);
          ((u16*)C0)[o] = h;
          ((u16*)C1)[o] = f2b(v - b2f(h));
        }
        if constexpr (EPI==SP_SCALE_F32 || EPI==SP_SCALE_STATS) ((float*)C0)[o] = v*scale;
        if constexpr (EPI==SP_QBG_F32)   ((float*)C0)[o] = gelu_f(v + bias[(row>>8)*512 + cn]);
      }
    }
  }

  if constexpr (EPI==SP_SCALE_STATS){
    // per-(row, 64-col group) partial max & expsum over this wave's 64 cols.
    const int g = blockIdx.x*2 + (wv&1);
    #pragma unroll
    for (int i=0;i<2;i++){
      #pragma unroll
      for (int p=0;p<4;p++){
        float mx = -3.4e38f;
        #pragma unroll
        for (int j=0;j<4;j++) mx = fmaxf(mx, acc[i][j][p]*scale);
        #pragma unroll
        for (int o=1;o<16;o<<=1) mx = fmaxf(mx, __shfl_xor(mx,o));
        float sm = 0.f;
        #pragma unroll
        for (int j=0;j<4;j++) sm += expf(acc[i][j][p]*scale - mx);
        #pragma unroll
        for (int o=1;o<16;o<<=1) sm += __shfl_xor(sm,o);
        if ((lane&15)==0){
          const int row = rb0 + i*16 + p;
          const long long pi = ((long long)z*2048 + row)*32 + g;
          pm[pi] = mx; ps[pi] = sm;
        }
      }
    }
  }
}

// merge 32 partials/row via exact log-sum-exp merge -> mrow/drow per z-half.
__global__ __launch_bounds__(256)
void merge_stats(const float* __restrict__ pm, const float* __restrict__ ps,
                 float* __restrict__ m0o, float* __restrict__ d0o,
                 float* __restrict__ m1o, float* __restrict__ d1o){
  const int wv = threadIdx.x>>6, lane = threadIdx.x&63;
  const int row = blockIdx.x*8 + wv*2 + (lane>>5);   // 0..4095
  const int g = lane & 31;
  const long long pi = (long long)row*32 + g;
  const float mg = pm[pi];
  float m = mg;
  #pragma unroll
  for (int o=1;o<32;o<<=1) m = fmaxf(m, __shfl_xor(m,o));
  float s = ps[pi] * expf(mg - m);
  #pragma unroll
  for (int o=1;o<32;o<<=1) s += __shfl_xor(s,o);
  if (g==0){
    if (row < 2048){ m0o[row]=m; d0o[row]=s; }
    else           { m1o[row-2048]=m; d1o[row-2048]=s; }
  }
}

// ---------------- prep kernels ----------------
__global__ void transpose_w(const float* __restrict__ in, u16* __restrict__ out, int rows, int cols){
  __shared__ float tl[32][33];
  const long long zo = (long long)blockIdx.z*rows*cols;
  const int c0 = blockIdx.x*32, r0 = blockIdx.y*32;
  const int tx = threadIdx.x, ty = threadIdx.y;
  #pragma unroll
  for (int yy=ty; yy<32; yy+=8) tl[yy][tx] = in[zo + (long long)(r0+yy)*cols + (c0+tx)];
  __syncthreads();
  #pragma unroll
  for (int yy=ty; yy<32; yy+=8) out[zo + (long long)(c0+yy)*rows + (r0+tx)] = f2b(tl[tx][yy]);
}

__global__ void split_transpose_w(const float* __restrict__ in, u16* __restrict__ outH,
                                  u16* __restrict__ outL, int rows, int cols){
  __shared__ float tl[32][33];
  const long long zo = (long long)blockIdx.z*rows*cols;
  const int c0 = blockIdx.x*32, r0 = blockIdx.y*32;
  const int tx = threadIdx.x, ty = threadIdx.y;
  #pragma unroll
  for (int yy=ty; yy<32; yy+=8) tl[yy][tx] = in[zo + (long long)(r0+yy)*cols + (c0+tx)];
  __syncthreads();
  #pragma unroll
  for (int yy=ty; yy<32; yy+=8){
    const float v = tl[tx][yy];
    const u16 h = f2b(v);
    const long long o = zo + (long long)(c0+yy)*rows + (r0+tx);
    outH[o] = h;
    outL[o] = f2b(v - b2f(h));
  }
}

__global__ void split_f32_k(const float* __restrict__ in, u16* __restrict__ oh,
                            u16* __restrict__ ol, int n4){
  const int i = blockIdx.x*256 + threadIdx.x;
  if (i < n4){
    const float4 v = ((const float4*)in)[i];
    u16x4 hh, ll;
    hh.x=f2b(v.x); ll.x=f2b(v.x-b2f(hh.x));
    hh.y=f2b(v.y); ll.y=f2b(v.y-b2f(hh.y));
    hh.z=f2b(v.z); ll.z=f2b(v.z-b2f(hh.z));
    hh.w=f2b(v.w); ll.w=f2b(v.w-b2f(hh.w));
    ((u16x4*)oh)[i] = hh;
    ((u16x4*)ol)[i] = ll;
  }
}

__global__ void zero_f32(float* __restrict__ p, int n){
  const int i = blockIdx.x*256 + threadIdx.x;
  if (i < n) p[i] = 0.f;
}

__global__ void init_queries(const float* __restrict__ pb, float* __restrict__ q){
  const int i = blockIdx.x*256 + threadIdx.x;
  if (i < 12288) q[i] = pb[(i>>12)*1024 + (i&1023)];
}
__global__ void init_qpart(const float* __restrict__ rb1, float* __restrict__ qp){
  const int i = blockIdx.x*256 + threadIdx.x;
  if (i < 6144) qp[i] = rb1[i&511];
}

__global__ void ws_report(float* __restrict__ out, int n4, float val){
  const int i = blockIdx.x*256 + threadIdx.x;
  if (i < n4){
    float4 z; z.x = (i==0)? val : 0.f; z.y=0.f; z.z=0.f; z.w=0.f;
    ((float4*)out)[i] = z;
  }
}

// ---------------- pooling (fp32 scores) ----------------
// col mean over softmax rows; z dim picks scoresA/scoresB + stats pair.
__global__ void col_mean2(const float* __restrict__ S, long long sz,
                          const float* __restrict__ m0a, const float* __restrict__ den0,
                          const float* __restrict__ m1a, const float* __restrict__ den1,
                          float* __restrict__ w){
  const int zz = blockIdx.z;
  const float* m   = zz ? m1a : m0a;
  const float* den = zz ? den1 : den0;
  const int tc = blockIdx.x*256 + threadIdx.x;
  const int s0 = blockIdx.y*64;
  const float* p = S + (long long)zz*sz + (long long)s0*2048 + tc;
  float acc = 0.f;
  for (int s=0;s<64;s++)
    acc += expf(p[(long long)s<<11] - m[s0+s]) * (1.0f/den[s0+s]);
  atomicAdd(&w[zz*2048 + tc], acc * (1.f/2048.f));
}

// pooled[b][d] += tile sums; grid (4,16) per retriever (R6-proven)
__global__ __launch_bounds__(256)
void pooled_par(const u16* __restrict__ qfh, const u16* __restrict__ qfl,
                const float* __restrict__ w, float* __restrict__ pooled){
  const int b = blockIdx.x, tt0 = blockIdx.y*128;
  const int t = threadIdx.x;
  __shared__ float wsh[128];
  if (t < 128) wsh[t] = w[b*2048 + tt0 + t];
  __syncthreads();
  const long long base = (long long)b*2097152 + (long long)tt0*1024;
  const u16* ph = qfh + base;
  const u16* pl = qfl + base;
  float acc[4] = {0.f,0.f,0.f,0.f};
  for (int s=0; s<128; s++){
    const float wt = wsh[s];
    const long long o = (long long)s*1024;
    #pragma unroll
    for (int k=0;k<4;k++){
      const int dd = t + k*256;
      acc[k] += wt*(b2f(ph[o+dd]) + b2f(pl[o+dd]));
    }
  }
  #pragma unroll
  for (int k=0;k<4;k++) atomicAdd(&pooled[b*1024 + t + k*256], acc[k]);
}

__global__ __launch_bounds__(1024)
void pool_ln(const float* __restrict__ pooled, const float* __restrict__ pg,
             const float* __restrict__ pb, float* __restrict__ plbuf){
  const int z = blockIdx.x, r = z>>2, d = threadIdx.x;
  const float v = pooled[z*1024+d];
  const float mean = blockRedSum(v) * (1.f/1024.f);
  const float df = v - mean;
  const float var = blockRedSum(df*df) * (1.f/1024.f);
  plbuf[z*1024+d] = df*rsqrtf(var+1e-5f)*pg[r*1024+d] + pb[r*1024+d];
}

__global__ __launch_bounds__(256)
void query_accum(const float* __restrict__ plbuf, const float* __restrict__ pw,
                 float* __restrict__ queries){
  const int z = blockIdx.x, r = z>>2, k0 = blockIdx.y*32;
  const int t = threadIdx.x;
  __shared__ float pls[32];
  if (t < 32) pls[t] = plbuf[z*1024 + k0 + t];
  __syncthreads();
  const float* wp = pw + (long long)r*1048576 + (long long)k0*1024;
  float acc[4] = {0.f,0.f,0.f,0.f};
  for (int s=0;s<32;s++){
    const float wv = pls[s];
    #pragma unroll
    for (int c=0;c<4;c++) acc[c] += wv*wp[s*1024 + t + c*256];
  }
  #pragma unroll
  for (int c=0;c<4;c++) atomicAdd(&queries[z*1024 + t + c*256], acc[c]);
}

__global__ __launch_bounds__(256)
void qpart_accum(const float* __restrict__ queries, const float* __restrict__ rw1,
                 float* __restrict__ qpart){
  const int z = blockIdx.x, k0 = blockIdx.y*64;
  const int t = threadIdx.x;
  __shared__ float qs[64];
  if (t < 64) qs[t] = queries[z*1024 + k0 + t];
  __syncthreads();
  const float* wp = rw1 + 1024*512 + (long long)k0*512;
  float acc[2] = {0.f,0.f};
  for (int s=0;s<64;s++){
    const float wv = qs[s];
    #pragma unroll
    for (int c=0;c<2;c++) acc[c] += wv*wp[s*512 + t + c*256];
  }
  #pragma unroll
  for (int c=0;c<2;c++) atomicAdd(&qpart[z*512 + t + c*256], acc[c]);
}

__global__ void rel_score_f32(const float* __restrict__ h, const float* __restrict__ w2,
                              const float* __restrict__ b2p, float* __restrict__ relv){
  const int row = blockIdx.x*4 + (threadIdx.x>>6);
  const int lane = threadIdx.x & 63;
  const float* p = h + (long long)row*512;
  float a = 0.f;
  #pragma unroll
  for (int k=0;k<8;k++){ const int idx = lane + k*64; a += p[idx]*w2[idx]; }
  a = waveRedSum(a);
  if (lane==0){
    const float lg = a + b2p[0];
    relv[row] = 1.f/(1.f+expf(-lg));
  }
}

// ---------------- selection ----------------
__global__ __launch_bounds__(768)
void select_topk(const float* __restrict__ relv, int* __restrict__ selidx,
                 int* __restrict__ neff, int* __restrict__ anyv){
  const int b = blockIdx.x, c = threadIdx.x;
  __shared__ float rv[768];
  __shared__ int cnt;
  rv[c] = relv[(((c>>8)*4)+b)*256 + (c&255)];
  if (c==0) cnt = 0;
  __syncthreads();
  const float mine = rv[c];
  const bool valid = (mine >= 0.5f);
  int rank = 0;
  for (int j=0;j<768;j++){
    const float vj = rv[j];
    if (vj >= 0.5f && (vj > mine || (vj == mine && j < c))) rank++;
  }
  if (valid && rank < 256){
    const int s = atomicAdd(&cnt, 1);
    selidx[b*256 + s] = c;
  }
  __syncthreads();
  if (c==0){ neff[b] = cnt; anyv[b] = (cnt>0) ? 1 : 0; }
}

__global__ void gather_sel(const u16* __restrict__ rb16, const int* __restrict__ selidx,
                           const int* __restrict__ neff, u16* __restrict__ seltok){
  const int slot = blockIdx.x, b = blockIdx.y, tid = threadIdx.x;
  uint2 val; val.x=0u; val.y=0u;
  if (slot < neff[b]){
    const int c = selidx[b*256+slot];
    const uint2* src = (const uint2*)(rb16 + (long long)(((c>>8)*4+b)*256 + (c&255))*1024);
    val = src[tid];
  }
  ((uint2*)(seltok + (long long)(b*256+slot)*1024))[tid] = val;
}

__global__ void attn_softmax(u16* __restrict__ S, const int* __restrict__ neff){
  const int ri = blockIdx.x*4 + (threadIdx.x>>6);
  const int lane = threadIdx.x & 63;
  const int b = ri >> 14;
  const int ne = neff[b];
  u16* p = S + (long long)ri*256 + lane*4;
  if (ne == 0){ uint2 zz; zz.x=0u; zz.y=0u; *(uint2*)p = zz; return; }
  uint2 raw = *(const uint2*)p;
  u16 uu[4] = {(u16)(raw.x&0xffffu),(u16)(raw.x>>16),(u16)(raw.y&0xffffu),(u16)(raw.y>>16)};
  float xs[4];
  #pragma unroll
  for (int q2=0;q2<4;q2++){ const int tt = lane*4+q2; xs[q2] = (tt<ne)? b2f(uu[q2]) : -1e30f; }
  float mx = fmaxf(fmaxf(xs[0],xs[1]),fmaxf(xs[2],xs[3]));
  mx = waveRedMax(mx);
  float e[4]; float sm=0.f;
  #pragma unroll
  for (int q2=0;q2<4;q2++){ e[q2] = (lane*4+q2<ne)? expf(xs[q2]-mx) : 0.f; sm += e[q2]; }
  sm = waveRedSum(sm);
  const float inv = 1.f/sm;
  #pragma unroll
  for (int q2=0;q2<4;q2++) uu[q2] = f2b(e[q2]*inv);
  raw.x = (u32)uu[0] | ((u32)uu[1]<<16);
  raw.y = (u32)uu[2] | ((u32)uu[3]<<16);
  *(uint2*)p = raw;
}

__global__ void final_ln(const float* __restrict__ x, const u16* __restrict__ fused,
                         const float* __restrict__ g, const float* __restrict__ bb,
                         const int* __restrict__ anyv, float* __restrict__ out){
  const int row = blockIdx.x; const int b = row>>11; const int tid = threadIdx.x;
  const float4 xv = ((const float4*)(x + (long long)row*1024))[tid];
  const uint2 fv = ((const uint2*)(fused + (long long)row*1024))[tid];
  const float e0 = xv.x + b2f((u16)(fv.x&0xffffu));
  const float e1 = xv.y + b2f((u16)(fv.x>>16));
  const float e2 = xv.z + b2f((u16)(fv.y&0xffffu));
  const float e3 = xv.w + b2f((u16)(fv.y>>16));
  const float mean = blockRedSum(e0+e1+e2+e3) * (1.f/1024.f);
  const float d0=e0-mean, d1=e1-mean, d2=e2-mean, d3=e3-mean;
  const float var = blockRedSum(d0*d0+d1*d1+d2*d2+d3*d3) * (1.f/1024.f);
  const float inv = rsqrtf(var + 1e-5f);
  const float4 gv = ((const float4*)g)[tid];
  const float4 bv = ((const float4*)bb)[tid];
  float4 o;
  if (anyv[b]){
    o.x = d0*inv*gv.x + bv.x; o.y = d1*inv*gv.y + bv.y;
    o.z = d2*inv*gv.z + bv.z; o.w = d3*inv*gv.w + bv.w;
  } else o = xv;
  ((float4*)(out + (long long)row*1024))[tid] = o;
}

// ============================================================================
extern "C" void kernel_launch(void* const* d_in, const int* in_sizes, int n_in,
                              void* d_out, int out_size, void* d_ws, size_t ws_size,
                              hipStream_t stream) {
  (void)in_sizes; (void)n_in;
  const float* x      = (const float*)d_in[0];
  const float* retr   = (const float*)d_in[1];
  const float* qg_w1  = (const float*)d_in[2];
  const float* qg_b1  = (const float*)d_in[3];
  const float* qg_w2  = (const float*)d_in[4];
  const float* qg_b2  = (const float*)d_in[5];
  const float* pln_g  = (const float*)d_in[6];
  const float* pln_b  = (const float*)d_in[7];
  const float* pool_w = (const float*)d_in[8];
  const float* pool_b = (const float*)d_in[9];
  const float* rel_w1 = (const float*)d_in[10];
  const float* rel_b1 = (const float*)d_in[11];
  const float* rel_w2 = (const float*)d_in[12];
  const float* rel_b2 = (const float*)d_in[13];
  const float* in_w   = (const float*)d_in[14];
  const float* in_b   = (const float*)d_in[15];
  const float* out_w  = (const float*)d_in[16];
  const float* out_b  = (const float*)d_in[17];
  const float* fln_g  = (const float*)d_in[18];
  const float* fln_b  = (const float*)d_in[19];
  float* out = (float*)d_out;
  char* ws = (char*)d_ws;

  const size_t MB = 1u<<20;
  const size_t REQUIRED = 131*MB;
  if (ws_size < REQUIRED){
    ws_report<<<(out_size/4 + 255)/256, 256, 0, stream>>>(out, out_size/4, (float)(ws_size>>20));
    return;
  }

  // ---- layout per header comment ----
  u16* qg1Th = (u16*)(ws + 0*MB);        // [P->A]
  u16* qg1Tl = (u16*)(ws + 6*MB);
  u16* qg2Th = (u16*)(ws + 12*MB);
  u16* qg2Tl = (u16*)(ws + 18*MB);
  u16* xh    = (u16*)(ws + 24*MB);       // [P->A,F]
  u16* xl    = (u16*)(ws + 40*MB);       // [P->A]
  u16* qfh   = (u16*)(ws + 56*MB);       // per-retriever [A->B]
  u16* qfl   = (u16*)(ws + 72*MB);
  u16* t1h   = (u16*)(ws + 88*MB);       // [A scratch]
  u16* t1l   = (u16*)(ws + 104*MB);      // [A scratch]
  float* scoresA = (float*)(ws + 88*MB); // [B] over dead t1h
  float* scoresB = (float*)(ws + 104*MB);// [B] over dead t1l
  // stage D/E overlays (qg weights dead after stage A):
  u16* rh    = (u16*)(ws + 0*MB);        // 6  [D,E]
  u16* rl    = (u16*)(ws + 6*MB);        // 6  [D]
  u16* relTh = (u16*)(ws + 12*MB);       // 1  [D]
  u16* relTl = (u16*)(ws + 13*MB);       // 1  [D]
  u16* seltok= (u16*)(ws + 14*MB);       // 2  [E->F vproj]
  u16* kbuf  = (u16*)(ws + 16*MB);       // 2  [F, dead after QK^T]
  u16* VT    = (u16*)(ws + 18*MB);       // 2  [F, dead after AV]
  float* hbuf= (float*)(ws + 88*MB);     // 6  [D] over dead scoresA
  // stage F overlays:
  u16* inT   = (u16*)(ws + 40*MB);       // 6  over dead xl
  u16* outT  = (u16*)(ws + 46*MB);       // 2
  u16* qbuf  = (u16*)(ws + 56*MB);       // 16 over dead qfh
  u16* fused = (u16*)(ws + 72*MB);       // 16 over dead qfl
  u16* Sattn = (u16*)(ws + 88*MB);       // 32 over dead scores
  u16* attnout=(u16*)(ws + 0*MB);        // 16 over dead rh/rl/relT/seltok
  char* SM = ws + 120*MB;
  float* wbuf    = (float*)(SM);            // 96 KB [12][2048]
  float* pooledB = (float*)(SM + 98304);    // 48 KB
  float* plbuf   = (float*)(SM + 147456);   // 48 KB
  float* queries = (float*)(SM + 196608);   // 48 KB
  float* qpart   = (float*)(SM + 245760);   // 24 KB
  float* relv    = (float*)(SM + 270336);   // 12 KB
  int*   selidx  = (int*)(SM + 282624);
  int*   neff    = (int*)(SM + 286720);
  int*   anyv    = (int*)(SM + 286784);
  float* mrow0   = (float*)(SM + 286848);
  float* drow0   = (float*)(SM + 295040);
  float* mrow1   = (float*)(SM + 303232);
  float* drow1   = (float*)(SM + 311424);
  float* partM   = (float*)(SM + 512*1024);   // 512 KB: 4096 rows x 32 groups
  float* partS   = (float*)(SM + 1536*1024);  // 512 KB

  dim3 b256(256);
  dim3 b512(512);
  dim3 tb(32,8);
  const long long SCZ = (long long)(16*MB)/4;   // scoresA -> scoresB (4,194,304 floats)

  // --- prep ---
  split_transpose_w<<<dim3(32,32,3), tb, 0, stream>>>(qg_w1, qg1Th, qg1Tl, 1024, 1024);
  split_transpose_w<<<dim3(32,32,3), tb, 0, stream>>>(qg_w2, qg2Th, qg2Tl, 1024, 1024);
  split_f32_k<<<8192, b256, 0, stream>>>(x, xh, xl, 2097152);
  zero_f32<<<144, b256, 0, stream>>>(wbuf, 36864);   // wbuf + pooledB

  // --- stages A+B interleaved per retriever (128^2 tiles, 512-thr blocks) ---
  for (int r = 0; r < 3; r++){
    const long long wo = (long long)r*1048576;
    gemm_nt_split<SP_GELU_SPLIT><<<dim3(8,64,1), b512, 0, stream>>>(
        xh, xl, 1024, 0,  qg1Th+wo, qg1Tl+wo, 1024, 0,
        t1h, t1l, 1024, 0,  qg_b1+r*1024, 1.f, 1024, nullptr, nullptr);
    gemm_nt_split<SP_BIAS_SPLIT><<<dim3(8,64,1), b512, 0, stream>>>(
        t1h, t1l, 1024, 0,  qg2Th+wo, qg2Tl+wo, 1024, 0,
        qfh, qfl, 1024, 0,  qg_b2+r*1024, 1.f, 1024, nullptr, nullptr);
    for (int p2 = 0; p2 < 2; p2++){
      const long long qo = (long long)(p2*2)*2097152;
      gemm_nt_split<SP_SCALE_STATS><<<dim3(16,16,2), b512, 0, stream>>>(
          qfh+qo, qfl+qo, 1024, 2097152,  qfh+qo, qfl+qo, 1024, 2097152,
          scoresA, nullptr, 2048, SCZ,  nullptr, 0.03125f, 1024, partM, partS);
      merge_stats<<<512, b256, 0, stream>>>(partM, partS, mrow0, drow0, mrow1, drow1);
      col_mean2<<<dim3(8,32,2), b256, 0, stream>>>(
          scoresA, SCZ, mrow0, drow0, mrow1, drow1, wbuf + (r*4+p2*2)*2048);
    }
    pooled_par<<<dim3(4,16), b256, 0, stream>>>(qfh, qfl, wbuf + r*8192, pooledB + r*4096);
  }
  pool_ln<<<12, 1024, 0, stream>>>(pooledB, pln_g, pln_b, plbuf);
  init_queries<<<48, b256, 0, stream>>>(pool_b, queries);
  query_accum<<<dim3(12,32), b256, 0, stream>>>(plbuf, pool_w, queries);

  // --- stage D prep (qg weights dead now) + relevance scorer ---
  split_f32_k<<<3072, b256, 0, stream>>>(retr, rh, rl, 786432);
  split_transpose_w<<<dim3(16,32,1), tb, 0, stream>>>(rel_w1, relTh, relTl, 1024, 512);
  init_qpart<<<24, b256, 0, stream>>>(rel_b1, qpart);
  qpart_accum<<<dim3(12,16), b256, 0, stream>>>(queries, rel_w1, qpart);
  gemm_nt_split<SP_QBG_F32><<<dim3(4,24,1), b512, 0, stream>>>(
      rh, rl, 1024, 0,  relTh, relTl, 1024, 0,  hbuf, nullptr, 512, 0,  qpart, 1.f, 1024,
      nullptr, nullptr);
  rel_score_f32<<<768, b256, 0, stream>>>(hbuf, rel_w2, rel_b2, relv);

  // --- stage E ---
  select_topk<<<4, 768, 0, stream>>>(relv, selidx, neff, anyv);
  gather_sel<<<dim3(256,4), b256, 0, stream>>>(rh, selidx, neff, seltok);

  // --- stage F ---
  transpose_w<<<dim3(32,32,3), tb, 0, stream>>>(in_w,  inT,  1024, 1024);
  transpose_w<<<dim3(32,32,1), tb, 0, stream>>>(out_w, outT, 1024, 1024);
  gemm_nt<EPI_BIAS><<<dim3(8,64,1), b512, 0, stream>>>(
      xh,1024,0,0,  inT,1024,0,0,  qbuf,1024,0,0,  in_b,0, 1.f, 1024, 1);
  gemm_nt<EPI_BIAS><<<dim3(8,8,1), b512, 0, stream>>>(
      seltok,1024,0,0,  inT+1048576,1024,0,0,  kbuf,1024,0,0,  in_b+1024,0, 1.f, 1024, 1);
  gemm_nt<EPI_VT><<<dim3(8,8,1), b512, 0, stream>>>(
      seltok,1024,0,0,  inT+2097152,1024,0,0,  VT,0,0,0,  in_b+2048,0, 1.f, 1024, 1);
  gemm_nt<EPI_SCALE><<<dim3(2,16,32), b512, 0, stream>>>(
      qbuf,1024,2097152,128,  kbuf,1024,262144,128,  Sattn,256,4194304,524288,
      (const float*)nullptr,0, 0.08838834764831845f, 128, 8);
  attn_softmax<<<16384, b256, 0, stream>>>(Sattn, neff);
  gemm_nt<EPI_NONE><<<dim3(1,16,32), b512, 0, stream>>>(
      Sattn,256,4194304,524288,  VT,256,262144,32768,  attnout,1024,2097152,128,
      (const float*)nullptr,0, 1.f, 256, 8);
  gemm_nt<EPI_BIAS><<<dim3(8,64,1), b512, 0, stream>>>(
      attnout,1024,0,0,  outT,1024,0,0,  fused,1024,0,0,  out_b,0, 1.f, 1024, 1);
  final_ln<<<8192, b256, 0, stream>>>(x, fused, fln_g, fln_b, anyv, out);
}